// Round 15
// baseline (5960.239 us; speedup 1.0000x reference)
//
#include <hip/hip_runtime.h>
#include <math.h>

#define T_STEPS 64
#define BB 64
#define LL 2048
#define EE 128
#define HH 256
#define NCHUNK 32
#define LCHUNK (LL / NCHUNK) /* 64 */

__device__ __forceinline__ float fexp(float x) {
    return __builtin_amdgcn_exp2f(x * 1.44269504088896340736f);
}
__device__ __forceinline__ float fsig(float x) {
    return __builtin_amdgcn_rcpf(1.f + __builtin_amdgcn_exp2f(-1.44269504088896340736f * x));
}
__device__ __forceinline__ float ftanh(float x) {
    float xc = fminf(fmaxf(x, -20.f), 20.f);
    float p = __builtin_amdgcn_exp2f(2.885390081777926814f * xc); // e^{2x}
    return (p - 1.f) * __builtin_amdgcn_rcpf(p + 1.f);
}
__device__ __forceinline__ unsigned int bfr(float x) {
    unsigned int u = __float_as_uint(x);
    return (u + 0x7FFFu + ((u >> 16) & 1u)) >> 16;
}
__device__ __forceinline__ void bf8x(const uint4 q, float* f) {
    f[0] = __uint_as_float(q.x << 16); f[1] = __uint_as_float(q.x & 0xFFFF0000u);
    f[2] = __uint_as_float(q.y << 16); f[3] = __uint_as_float(q.y & 0xFFFF0000u);
    f[4] = __uint_as_float(q.z << 16); f[5] = __uint_as_float(q.z & 0xFFFF0000u);
    f[6] = __uint_as_float(q.w << 16); f[7] = __uint_as_float(q.w & 0xFFFF0000u);
}
__device__ __forceinline__ void load8(const float* p, float* d) {
    float4 a = *(const float4*)p, b = *(const float4*)(p + 4);
    d[0]=a.x; d[1]=a.y; d[2]=a.z; d[3]=a.w; d[4]=b.x; d[5]=b.y; d[6]=b.z; d[7]=b.w;
}

// ---------------------------------------------------------------------------
// K0: fp32 -> bf16 conversion of enc + zero the per-step accumulators and
// election counters (plain stores; dispatch-boundary writeback publishes).
// ---------------------------------------------------------------------------
__global__ __launch_bounds__(256) void conv_kernel(
    const float4* __restrict__ enc, uint4* __restrict__ encb,
    float* __restrict__ ctx_acc, float* __restrict__ S_acc,
    int* __restrict__ cnt)
{
    const int n = BB * LL * HH / 8;
    const int gt = blockIdx.x * 256 + threadIdx.x;
    for (int i = gt; i < n; i += gridDim.x * 256) {
        const float4 a = enc[2 * i], c = enc[2 * i + 1];
        uint4 o;
        o.x = bfr(a.x) | (bfr(a.y) << 16);
        o.y = bfr(a.z) | (bfr(a.w) << 16);
        o.z = bfr(c.x) | (bfr(c.y) << 16);
        o.w = bfr(c.z) | (bfr(c.w) << 16);
        encb[i] = o;
    }
    const int na = T_STEPS * BB * HH;
    for (int i = gt; i < na; i += gridDim.x * 256) ctx_acc[i] = 0.f;
    for (int i = gt; i < T_STEPS * BB; i += gridDim.x * 256) {
        S_acc[i] = 0.f;
        cnt[i] = 0;
    }
}

// ---------------------------------------------------------------------------
// K1: prologue (once): x(0) (ctx=0), c/h(0), df(0). Grid BB, 256 threads.
// ---------------------------------------------------------------------------
__global__ __launch_bounds__(256) void pre_kernel(
    const float* __restrict__ dec_in,
    const float* __restrict__ init_c, const float* __restrict__ init_h,
    const float* __restrict__ Wx, const float* __restrict__ bx,
    const float* __restrict__ Wl, const float* __restrict__ bl,
    const float* __restrict__ Ws, const float* __restrict__ bs,
    float* __restrict__ x_hist, float* __restrict__ c_hist,
    float* __restrict__ h_hist, float* __restrict__ df_ws)
{
    const int b = blockIdx.x;
    const int tid = threadIdx.x;
    __shared__ float sxh[EE + HH];
    __shared__ float red[256];
    __shared__ float scl[HH], shl[HH];

    sxh[EE + tid] = init_h[(size_t)b * HH + tid];
    __syncthreads();

    {
        const int j = tid & 127, q = tid >> 7;
        float a = 0.f;
        #pragma unroll 8
        for (int r = q * 64; r < q * 64 + 64; ++r)
            a += dec_in[(size_t)b * EE + r] * Wx[(size_t)r * EE + j];
        red[tid] = a;
    }
    __syncthreads();
    if (tid < EE) {
        const float xv = fmaxf(red[tid] + red[128 + tid] + bx[tid], 0.f);
        sxh[tid] = xv;
        x_hist[(size_t)b * EE + tid] = xv;
    }
    __syncthreads();

    {
        const int u = tid;
        float zi = bl[u], zf = bl[256 + u], zg = bl[512 + u], zo = bl[768 + u];
        const float* w = Wl + u;
        #pragma unroll 4
        for (int r = 0; r < EE + HH; ++r) {
            const float f = sxh[r];
            zi += f * w[(size_t)r * 1024];
            zf += f * w[(size_t)r * 1024 + 256];
            zg += f * w[(size_t)r * 1024 + 512];
            zo += f * w[(size_t)r * 1024 + 768];
        }
        const float cp = init_c[(size_t)b * HH + u];
        const float cn = fsig(zf) * cp + fsig(zi) * ftanh(zg);
        const float hn = fsig(zo) * ftanh(cn);
        c_hist[(size_t)b * HH + u] = cn;
        h_hist[(size_t)b * HH + u] = hn;
        scl[u] = cn; shl[u] = hn;
    }
    __syncthreads();

    {
        const int j = tid;
        float a = 0.f;
        #pragma unroll 8
        for (int r = 0; r < HH; ++r) a += scl[r] * Ws[(size_t)r * HH + j];
        #pragma unroll 8
        for (int r = 0; r < HH; ++r) a += shl[r] * Ws[(size_t)(HH + r) * HH + j];
        df_ws[(size_t)b * HH + j] = ftanh(a + bs[j]);
    }
}

// ---------------------------------------------------------------------------
// K2: ONE dispatch per step. Attention for step t (depth-1 prefetch, r12
// core) + step-(t-1) epilogue (attns/cov rmw) + RELAXED-atomic partial
// accumulation into per-step slots + last-block-per-batch tail:
// ctx(t) -> x(t+1) -> z/c,h(t+1) -> df(t+1).
// NO acq_rel, NO threadfence: plain atomicAdd executes at the L3 coherence
// point (r13's 2048x buffer_wbl2/inv was the regression cause).
// Grid: NCHUNK*BB = 2048 blocks, 256 threads.
// ---------------------------------------------------------------------------
__global__ __launch_bounds__(256) void attn_kernel(
    const uint4* __restrict__ encb, const float* __restrict__ mask,
    float* __restrict__ cov, float* __restrict__ df_ws,
    const float* __restrict__ v, const float* __restrict__ wc,
    float* __restrict__ e_ws, float* __restrict__ attns,
    float* __restrict__ is_ws,
    float* __restrict__ ctx_acc, float* __restrict__ S_acc,
    int* __restrict__ cnt,
    const float* __restrict__ dec_in,
    const float* __restrict__ Wx, const float* __restrict__ bx,
    const float* __restrict__ Wl, const float* __restrict__ bl,
    const float* __restrict__ Ws, const float* __restrict__ bs,
    float* __restrict__ ctx_hist, float* __restrict__ x_hist,
    float* __restrict__ c_hist, float* __restrict__ h_hist, int t)
{
    const int prev_t = t - 1;
    const int g = blockIdx.x;
    const int b = g & (BB - 1);
    const int chunk = g >> 6;
    const int tid = threadIdx.x;
    const int wave = tid >> 6;
    const int lane = tid & 63;
    const int hc = lane & 15;
    const int lsub = lane >> 4;
    const int l0 = chunk * LCHUNK + wave * (LCHUNK / 4);

    const float* e_prev = e_ws + (size_t)(prev_t & 1) * BB * LL;
    float* e_cur = e_ws + (size_t)(t & 1) * BB * LL;
    const float iSprev = (prev_t >= 0) ? is_ws[b] : 0.f;

    float mskv[4], covv[4], epv[4];
    #pragma unroll
    for (int mi = 0; mi < 4; ++mi) {
        const int idx = b * LL + l0 + mi * 4 + lsub;
        mskv[mi] = mask[idx];
        covv[mi] = (prev_t >= 0) ? cov[idx] : 0.f;
        epv[mi]  = (prev_t >= 0) ? e_prev[idx] : 0.f;
    }

    float dfv[16], vv[16], wcv[16];
    #pragma unroll
    for (int k = 0; k < 2; ++k) {
        load8(df_ws + b * HH + hc * 8 + 128 * k, dfv + 8 * k);
        load8(v + hc * 8 + 128 * k, vv + 8 * k);
        load8(wc + hc * 8 + 128 * k, wcv + 8 * k);
    }

    float cvv[4];
    #pragma unroll
    for (int mi = 0; mi < 4; ++mi) {
        const int l = l0 + mi * 4 + lsub;
        const int idx = b * LL + l;
        if (prev_t >= 0) {
            const float a = fexp(epv[mi]) * mskv[mi] * iSprev;
            cvv[mi] = covv[mi] + a;
            if (hc == 0) {
                cov[idx] = cvv[mi];
                attns[((size_t)prev_t * BB + b) * LL + l] = a;
            }
        } else {
            cvv[mi] = 0.f;
            if (hc == 0) cov[idx] = 0.f;
        }
    }

    const uint4* ep0 = encb + (size_t)(b * LL + l0 + lsub) * 32 + hc;

    float s = 0.f;
    float cacc[16];
    #pragma unroll
    for (int j = 0; j < 16; ++j) cacc[j] = 0.f;

    uint4 eA0 = ep0[0], eA1 = ep0[16];

    #pragma unroll
    for (int mi = 0; mi < 4; ++mi) {
        uint4 eB0 = {0,0,0,0}, eB1 = {0,0,0,0};
        if (mi < 3) { eB0 = ep0[(mi + 1) * 128]; eB1 = ep0[(mi + 1) * 128 + 16]; }

        float fe[16];
        bf8x(eA0, fe); bf8x(eA1, fe + 8);
        float pp = 0.f;
        #pragma unroll
        for (int j = 0; j < 16; ++j)
            pp += vv[j] * ftanh(fe[j] + dfv[j] + cvv[mi] * wcv[j]);
        pp += __shfl_xor(pp, 1);
        pp += __shfl_xor(pp, 2);
        pp += __shfl_xor(pp, 4);
        pp += __shfl_xor(pp, 8);
        const int l = l0 + mi * 4 + lsub;
        if (hc == 0) e_cur[b * LL + l] = pp;

        const float w = fexp(pp) * mskv[mi];   // bounded e -> no max shift
        s += w;
        #pragma unroll
        for (int j = 0; j < 16; ++j) cacc[j] += w * fe[j];
        eA0 = eB0; eA1 = eB1;
    }

    #pragma unroll
    for (int off = 16; off <= 32; off <<= 1) {
        s += __shfl_xor(s, off);
        #pragma unroll
        for (int j = 0; j < 16; ++j) cacc[j] += __shfl_xor(cacc[j], off);
    }

    __shared__ float lsum[4];
    __shared__ float lctx[4][HH];
    if (lsub == 0) {
        #pragma unroll
        for (int k = 0; k < 2; ++k)
            #pragma unroll
            for (int j = 0; j < 8; ++j)
                lctx[wave][hc * 8 + 128 * k + j] = cacc[k * 8 + j];
    }
    if (lane == 0) lsum[wave] = s;
    __syncthreads();

    // relaxed atomic accumulation at the coherence point (no L2 flush)
    atomicAdd(&ctx_acc[((size_t)t * BB + b) * HH + tid],
              lctx[0][tid] + lctx[1][tid] + lctx[2][tid] + lctx[3][tid]);
    if (tid == 0)
        atomicAdd(&S_acc[t * BB + b], lsum[0] + lsum[1] + lsum[2] + lsum[3]);

    // ---- last-block-per-batch election (relaxed; syncthreads drains vmcnt) ----
    __shared__ int s_last;
    __syncthreads();
    if (tid == 0)
        s_last = (atomicAdd(&cnt[t * BB + b], 1) == NCHUNK - 1) ? 1 : 0;
    __syncthreads();
    if (!s_last) return;

    // ======================= step tail (one block per batch) ================
    __shared__ float t_sctx[HH];
    __shared__ float t_sxh[EE + HH];
    __shared__ float t_red[256];
    __shared__ float t_scl[HH], t_shl[HH];
    __shared__ float t_S;

    // 1. ctx(t): coherent atomic reads of the accumulators
    {
        const float cs = atomicAdd(&ctx_acc[((size_t)t * BB + b) * HH + tid], 0.f);
        if (tid == 0) t_S = atomicAdd(&S_acc[t * BB + b], 0.f);
        __syncthreads();
        const float invS = 1.f / t_S;
        const float cx = cs * invS;
        t_sctx[tid] = cx;
        ctx_hist[((size_t)t * BB + b) * HH + tid] = cx;
        if (tid == 0) is_ws[b] = invS;
        t_sxh[EE + tid] = h_hist[((size_t)t * BB + b) * HH + tid];
    }
    __syncthreads();

    if (t + 1 >= T_STEPS) return;

    // 2. x(t+1) = relu([inp(t+1), ctx(t)] @ Wx + bx); 2 threads/col, K=192
    {
        const int j = tid & 127, q = tid >> 7;
        float a = 0.f;
        #pragma unroll 8
        for (int r = q * 192; r < q * 192 + 192; ++r) {
            const float f = (r < EE) ? dec_in[((size_t)(t + 1) * BB + b) * EE + r]
                                     : t_sctx[r - EE];
            a += f * Wx[(size_t)r * EE + j];
        }
        t_red[tid] = a;
    }
    __syncthreads();
    if (tid < EE) {
        const float xv = fmaxf(t_red[tid] + t_red[128 + tid] + bx[tid], 0.f);
        t_sxh[tid] = xv;
        x_hist[((size_t)(t + 1) * BB + b) * EE + tid] = xv;
    }
    __syncthreads();

    // 3. z(t+1): thread = unit, 4 gate-cols; K=384 from LDS, coalesced Wl
    {
        const int u = tid;
        float zi = bl[u], zf = bl[256 + u], zg = bl[512 + u], zo = bl[768 + u];
        const float* w = Wl + u;
        #pragma unroll 4
        for (int r = 0; r < EE + HH; ++r) {
            const float f = t_sxh[r];
            zi += f * w[(size_t)r * 1024];
            zf += f * w[(size_t)r * 1024 + 256];
            zg += f * w[(size_t)r * 1024 + 512];
            zo += f * w[(size_t)r * 1024 + 768];
        }
        const float cp = c_hist[((size_t)t * BB + b) * HH + u];
        const float cn = fsig(zf) * cp + fsig(zi) * ftanh(zg);
        const float hn = fsig(zo) * ftanh(cn);
        c_hist[((size_t)(t + 1) * BB + b) * HH + u] = cn;
        h_hist[((size_t)(t + 1) * BB + b) * HH + u] = hn;
        t_scl[u] = cn; t_shl[u] = hn;
    }
    __syncthreads();

    // 4. df(t+1) = tanh([c,h] @ Ws + bs): thread = col, K=512
    {
        const int j = tid;
        float a = 0.f;
        #pragma unroll 8
        for (int r = 0; r < HH; ++r) a += t_scl[r] * Ws[(size_t)r * HH + j];
        #pragma unroll 8
        for (int r = 0; r < HH; ++r) a += t_shl[r] * Ws[(size_t)(HH + r) * HH + j];
        df_ws[(size_t)b * HH + j] = ftanh(a + bs[j]);
    }
}

// ---------------------------------------------------------------------------
// K3: epilogue: attns[T-1], final cov, c/h outputs. Grid BB, 256 threads.
// ---------------------------------------------------------------------------
__global__ __launch_bounds__(256) void epi_kernel(
    const float* __restrict__ e_ws, const float* __restrict__ mask,
    const float* __restrict__ is_ws,
    const float* __restrict__ c_hist, const float* __restrict__ h_hist,
    float* __restrict__ attns, float* __restrict__ cov,
    float* __restrict__ c_out, float* __restrict__ h_out)
{
    const int b = blockIdx.x;
    const int j = threadIdx.x;
    const float iS = is_ws[b];
    const float* e_last = e_ws + (size_t)((T_STEPS - 1) & 1) * BB * LL;
    for (int i = 0; i < LL / 256; ++i) {
        const int l = i * 256 + j;
        const int idx = b * LL + l;
        const float a = fexp(e_last[idx]) * mask[idx] * iS;
        attns[((size_t)(T_STEPS - 1) * BB + b) * LL + l] = a;
        cov[idx] += a;
    }
    c_out[b * HH + j] = c_hist[((size_t)(T_STEPS - 1) * BB + b) * HH + j];
    h_out[b * HH + j] = h_hist[((size_t)(T_STEPS - 1) * BB + b) * HH + j];
}

// ---------------------------------------------------------------------------
// K4: batched outs + pgens. Grid 512 blocks = (t, 8-batch slice), 512 thr.
// ---------------------------------------------------------------------------
__global__ __launch_bounds__(512) void out_kernel(
    const float* __restrict__ h_hist, const float* __restrict__ ctx_hist,
    const float* __restrict__ c_hist, const float* __restrict__ x_hist,
    const float* __restrict__ Wo, const float* __restrict__ bo,
    const float* __restrict__ Wp, const float* __restrict__ bp,
    float* __restrict__ outs, float* __restrict__ pgens)
{
    const int t = blockIdx.x >> 3;
    const int b8 = blockIdx.x & 7;
    const int tid = threadIdx.x;
    __shared__ float hs[8 * 256], cts[8 * 256], cs2[8 * 256], xs[8 * 128];
    __shared__ float zbuf[8 * 256];

    for (int i = tid; i < 8 * 256; i += 512) {
        const int bl = i >> 8, j = i & 255;
        const size_t row = ((size_t)t * BB + b8 * 8 + bl) * HH;
        hs[i] = h_hist[row + j];
        cts[i] = ctx_hist[row + j];
        cs2[i] = c_hist[row + j];
    }
    for (int i = tid; i < 8 * 128; i += 512) {
        const int bl = i >> 7, j = i & 127;
        xs[i] = x_hist[((size_t)t * BB + b8 * 8 + bl) * EE + j];
    }
    __syncthreads();

    {
        const int j = tid & 255, rh = tid >> 8;
        float acc[8];
        #pragma unroll
        for (int bl = 0; bl < 8; ++bl) acc[bl] = 0.f;
        const int r0 = rh * 128;
        #pragma unroll 4
        for (int r = r0; r < r0 + 128; ++r) {
            const float w0 = Wo[(size_t)r * HH + j];
            const float w1 = Wo[(size_t)(256 + r) * HH + j];
            #pragma unroll
            for (int bl = 0; bl < 8; ++bl)
                acc[bl] += hs[bl * 256 + r] * w0 + cts[bl * 256 + r] * w1;
        }
        if (rh) {
            #pragma unroll
            for (int bl = 0; bl < 8; ++bl) zbuf[bl * 256 + j] = acc[bl];
        }
        __syncthreads();
        if (!rh) {
            #pragma unroll
            for (int bl = 0; bl < 8; ++bl)
                outs[((size_t)t * BB + b8 * 8 + bl) * HH + j] =
                    acc[bl] + zbuf[bl * 256 + j] + bo[j];
        }
    }

    {
        const int bl = tid >> 6, r64 = tid & 63;
        float pp = 0.f;
        for (int i = r64; i < 256; i += 64)
            pp += cts[bl * 256 + i] * Wp[i] + cs2[bl * 256 + i] * Wp[256 + i]
                + hs[bl * 256 + i] * Wp[512 + i];
        for (int i = r64; i < 128; i += 64)
            pp += xs[bl * 128 + i] * Wp[768 + i];
        #pragma unroll
        for (int off = 32; off; off >>= 1) pp += __shfl_xor(pp, off);
        if (r64 == 0)
            pgens[(size_t)t * BB + b8 * 8 + bl] = fsig(pp + bp[0]);
    }
}

extern "C" void kernel_launch(void* const* d_in, const int* in_sizes, int n_in,
                              void* d_out, int out_size, void* d_ws, size_t ws_size,
                              hipStream_t stream) {
    const float* dec_in = (const float*)d_in[0];
    const float* init_c = (const float*)d_in[1];
    const float* init_h = (const float*)d_in[2];
    const float* enc    = (const float*)d_in[3];
    const float* mask   = (const float*)d_in[4];
    const float* Wx = (const float*)d_in[5];
    const float* bx = (const float*)d_in[6];
    const float* Wl = (const float*)d_in[7];
    const float* bl = (const float*)d_in[8];
    const float* Ws = (const float*)d_in[9];
    const float* bs = (const float*)d_in[10];
    const float* v  = (const float*)d_in[11];
    const float* wc = (const float*)d_in[12];
    const float* Wp = (const float*)d_in[13];
    const float* bp = (const float*)d_in[14];
    const float* Wo = (const float*)d_in[15];
    const float* bo = (const float*)d_in[16];

    float* out   = (float*)d_out;
    float* outs  = out;                                   // T*B*H
    float* c_out = outs + (size_t)T_STEPS * BB * HH;      // B*H
    float* h_out = c_out + BB * HH;                       // B*H
    float* attns = h_out + BB * HH;                       // T*B*L
    float* pgens = attns + (size_t)T_STEPS * BB * LL;     // T*B
    float* cov   = pgens + T_STEPS * BB;                  // B*L

    float* ws     = (float*)d_ws;
    uint4* encb   = (uint4*)ws;                           // B*L*H bf16
    float* w      = ws + (size_t)BB * LL * HH / 2;
    float* e_ws   = w;    w += 2 * BB * LL;
    float* ctx_acc = w;   w += (size_t)T_STEPS * BB * HH; // per-step slots
    float* S_acc  = w;    w += T_STEPS * BB;
    float* x_hist = w;    w += (size_t)T_STEPS * BB * EE;
    float* df_ws  = w;    w += BB * HH;
    float* is_ws  = w;    w += BB;
    float* ctx_hist = w;  w += (size_t)T_STEPS * BB * HH;
    float* c_hist = w;    w += (size_t)T_STEPS * BB * HH;
    float* h_hist = w;    w += (size_t)T_STEPS * BB * HH;
    int* cnt      = (int*)w;                              // T*B counters

    conv_kernel<<<4096, 256, 0, stream>>>((const float4*)enc, encb,
        ctx_acc, S_acc, cnt);
    pre_kernel<<<BB, 256, 0, stream>>>(dec_in, init_c, init_h,
        Wx, bx, Wl, bl, Ws, bs, x_hist, c_hist, h_hist, df_ws);

    for (int t = 0; t < T_STEPS; ++t) {
        attn_kernel<<<NCHUNK * BB, 256, 0, stream>>>(encb, mask, cov, df_ws,
            v, wc, e_ws, attns, is_ws, ctx_acc, S_acc, cnt,
            dec_in, Wx, bx, Wl, bl, Ws, bs,
            ctx_hist, x_hist, c_hist, h_hist, t);
    }
    epi_kernel<<<BB, 256, 0, stream>>>(e_ws, mask, is_ws,
        c_hist, h_hist, attns, cov, c_out, h_out);
    out_kernel<<<512, 512, 0, stream>>>(h_hist, ctx_hist, c_hist, x_hist,
        Wo, bo, Wp, bp, outs, pgens);
}

// Round 16
// 4835.318 us; speedup vs baseline: 1.2326x; 1.2326x over previous
//
#include <hip/hip_runtime.h>
#include <math.h>

#define T_STEPS 64
#define BB 64
#define LL 2048
#define EE 128
#define HH 256
#define NCHUNK 32
#define LCHUNK (LL / NCHUNK) /* 64 */

__device__ __forceinline__ float fexp(float x) {
    return __builtin_amdgcn_exp2f(x * 1.44269504088896340736f);
}
__device__ __forceinline__ float fsig(float x) {
    return __builtin_amdgcn_rcpf(1.f + __builtin_amdgcn_exp2f(-1.44269504088896340736f * x));
}
__device__ __forceinline__ float ftanh(float x) {
    float xc = fminf(fmaxf(x, -20.f), 20.f);
    float p = __builtin_amdgcn_exp2f(2.885390081777926814f * xc); // e^{2x}
    return (p - 1.f) * __builtin_amdgcn_rcpf(p + 1.f);
}
__device__ __forceinline__ unsigned int bfr(float x) {
    unsigned int u = __float_as_uint(x);
    return (u + 0x7FFFu + ((u >> 16) & 1u)) >> 16;
}
__device__ __forceinline__ void bf8x(const uint4 q, float* f) {
    f[0] = __uint_as_float(q.x << 16); f[1] = __uint_as_float(q.x & 0xFFFF0000u);
    f[2] = __uint_as_float(q.y << 16); f[3] = __uint_as_float(q.y & 0xFFFF0000u);
    f[4] = __uint_as_float(q.z << 16); f[5] = __uint_as_float(q.z & 0xFFFF0000u);
    f[6] = __uint_as_float(q.w << 16); f[7] = __uint_as_float(q.w & 0xFFFF0000u);
}
__device__ __forceinline__ void load8(const float* p, float* d) {
    float4 a = *(const float4*)p, b = *(const float4*)(p + 4);
    d[0]=a.x; d[1]=a.y; d[2]=a.z; d[3]=a.w; d[4]=b.x; d[5]=b.y; d[6]=b.z; d[7]=b.w;
}

// ---------------------------------------------------------------------------
// K0: fp32 -> bf16 conversion of enc + zero per-step accumulators/counters.
// ---------------------------------------------------------------------------
__global__ __launch_bounds__(256) void conv_kernel(
    const float4* __restrict__ enc, uint4* __restrict__ encb,
    float* __restrict__ ctx_acc, float* __restrict__ S_acc,
    int* __restrict__ cnt)
{
    const int n = BB * LL * HH / 8;
    const int gt = blockIdx.x * 256 + threadIdx.x;
    for (int i = gt; i < n; i += gridDim.x * 256) {
        const float4 a = enc[2 * i], c = enc[2 * i + 1];
        uint4 o;
        o.x = bfr(a.x) | (bfr(a.y) << 16);
        o.y = bfr(a.z) | (bfr(a.w) << 16);
        o.z = bfr(c.x) | (bfr(c.y) << 16);
        o.w = bfr(c.z) | (bfr(c.w) << 16);
        encb[i] = o;
    }
    const int na = T_STEPS * BB * HH;
    for (int i = gt; i < na; i += gridDim.x * 256) ctx_acc[i] = 0.f;
    for (int i = gt; i < T_STEPS * BB; i += gridDim.x * 256) {
        S_acc[i] = 0.f;
        cnt[i] = 0;
    }
}

// ---------------------------------------------------------------------------
// K1: prologue (once): x(0) (ctx=0), c/h(0), df_part[0..3](0).
// Grid BB, 256 threads.
// ---------------------------------------------------------------------------
__global__ __launch_bounds__(256) void pre_kernel(
    const float* __restrict__ dec_in,
    const float* __restrict__ init_c, const float* __restrict__ init_h,
    const float* __restrict__ Wx, const float* __restrict__ bx,
    const float* __restrict__ Wl, const float* __restrict__ bl,
    const float* __restrict__ Ws,
    float* __restrict__ x_hist, float* __restrict__ c_hist,
    float* __restrict__ h_hist, float* __restrict__ df_part)
{
    const int b = blockIdx.x;
    const int tid = threadIdx.x;
    __shared__ float sxh[EE + HH];
    __shared__ float red[256];
    __shared__ float scl[HH], shl[HH];

    sxh[EE + tid] = init_h[(size_t)b * HH + tid];
    __syncthreads();

    {
        const int j = tid & 127, q = tid >> 7;
        float a = 0.f;
        #pragma unroll 8
        for (int r = q * 64; r < q * 64 + 64; ++r)
            a += dec_in[(size_t)b * EE + r] * Wx[(size_t)r * EE + j];
        red[tid] = a;
    }
    __syncthreads();
    if (tid < EE) {
        const float xv = fmaxf(red[tid] + red[128 + tid] + bx[tid], 0.f);
        sxh[tid] = xv;
        x_hist[(size_t)b * EE + tid] = xv;
    }
    __syncthreads();

    {
        const int u = tid;
        float zi = bl[u], zf = bl[256 + u], zg = bl[512 + u], zo = bl[768 + u];
        const float* w = Wl + u;
        #pragma unroll 4
        for (int r = 0; r < EE + HH; ++r) {
            const float f = sxh[r];
            zi += f * w[(size_t)r * 1024];
            zf += f * w[(size_t)r * 1024 + 256];
            zg += f * w[(size_t)r * 1024 + 512];
            zo += f * w[(size_t)r * 1024 + 768];
        }
        const float cp = init_c[(size_t)b * HH + u];
        const float cn = fsig(zf) * cp + fsig(zi) * ftanh(zg);
        const float hn = fsig(zo) * ftanh(cn);
        c_hist[(size_t)b * HH + u] = cn;
        h_hist[(size_t)b * HH + u] = hn;
        scl[u] = cn; shl[u] = hn;
    }
    __syncthreads();

    // df_part[s] = partial [c,h]@Ws over slice rows (no bias/tanh)
    for (int s = 0; s < 4; ++s) {
        const int j = tid;
        const int us = s * 64;
        float a = 0.f;
        #pragma unroll 8
        for (int u = 0; u < 64; ++u)
            a += scl[us + u] * Ws[(size_t)(us + u) * HH + j]
               + shl[us + u] * Ws[(size_t)(256 + us + u) * HH + j];
        df_part[((size_t)s * BB + b) * HH + j] = a;
    }
}

// ---------------------------------------------------------------------------
// K2: ONE dispatch per step. Attention (r12 depth-1 core; df completed from
// df_part) + step-(t-1) epilogue + relaxed-atomic partials + 4-WINNER
// election: blocks with cnt-rank 28..31 poll cnt==32 (all blocks co-resident
// at 2048 = exact max occupancy -> deadlock-free), then run tail slice
// s = rank-28: ctx -> x(t+1) -> z-slice -> c,h -> df_part[s].
// r15 lesson: single-winner tail = r11's 89us serial shape; 4 slices fix it.
// ---------------------------------------------------------------------------
__global__ __launch_bounds__(256) void attn_kernel(
    const uint4* __restrict__ encb, const float* __restrict__ mask,
    float* __restrict__ cov, float* __restrict__ df_part,
    const float* __restrict__ bs,
    const float* __restrict__ v, const float* __restrict__ wc,
    float* __restrict__ e_ws, float* __restrict__ attns,
    float* __restrict__ is_ws,
    float* __restrict__ ctx_acc, float* __restrict__ S_acc,
    int* __restrict__ cnt,
    const float* __restrict__ dec_in,
    const float* __restrict__ Wx, const float* __restrict__ bx,
    const float* __restrict__ Wl, const float* __restrict__ bl,
    const float* __restrict__ Ws,
    float* __restrict__ ctx_hist, float* __restrict__ x_hist,
    float* __restrict__ c_hist, float* __restrict__ h_hist, int t)
{
    const int prev_t = t - 1;
    const int g = blockIdx.x;
    const int b = g & (BB - 1);
    const int chunk = g >> 6;
    const int tid = threadIdx.x;
    const int wave = tid >> 6;
    const int lane = tid & 63;
    const int hc = lane & 15;
    const int lsub = lane >> 4;
    const int l0 = chunk * LCHUNK + wave * (LCHUNK / 4);

    const float* e_prev = e_ws + (size_t)(prev_t & 1) * BB * LL;
    float* e_cur = e_ws + (size_t)(t & 1) * BB * LL;
    const float iSprev = (prev_t >= 0) ? is_ws[b] : 0.f;

    float mskv[4], covv[4], epv[4];
    #pragma unroll
    for (int mi = 0; mi < 4; ++mi) {
        const int idx = b * LL + l0 + mi * 4 + lsub;
        mskv[mi] = mask[idx];
        covv[mi] = (prev_t >= 0) ? cov[idx] : 0.f;
        epv[mi]  = (prev_t >= 0) ? e_prev[idx] : 0.f;
    }

    // complete dec_feat: df = tanh(sum_s df_part + bs)
    float dfv[16], vv[16], wcv[16];
    #pragma unroll
    for (int k = 0; k < 2; ++k) {
        const int h = hc * 8 + 128 * k;
        float d0[8], d1[8], d2[8], d3[8], bsv[8];
        load8(df_part + (size_t)(0 * BB + b) * HH + h, d0);
        load8(df_part + (size_t)(1 * BB + b) * HH + h, d1);
        load8(df_part + (size_t)(2 * BB + b) * HH + h, d2);
        load8(df_part + (size_t)(3 * BB + b) * HH + h, d3);
        load8(bs + h, bsv);
        #pragma unroll
        for (int j = 0; j < 8; ++j)
            dfv[8 * k + j] = ftanh(d0[j] + d1[j] + d2[j] + d3[j] + bsv[j]);
        load8(v + h, vv + 8 * k);
        load8(wc + h, wcv + 8 * k);
    }

    float cvv[4];
    #pragma unroll
    for (int mi = 0; mi < 4; ++mi) {
        const int l = l0 + mi * 4 + lsub;
        const int idx = b * LL + l;
        if (prev_t >= 0) {
            const float a = fexp(epv[mi]) * mskv[mi] * iSprev;
            cvv[mi] = covv[mi] + a;
            if (hc == 0) {
                cov[idx] = cvv[mi];
                attns[((size_t)prev_t * BB + b) * LL + l] = a;
            }
        } else {
            cvv[mi] = 0.f;
            if (hc == 0) cov[idx] = 0.f;
        }
    }

    const uint4* ep0 = encb + (size_t)(b * LL + l0 + lsub) * 32 + hc;

    float s = 0.f;
    float cacc[16];
    #pragma unroll
    for (int j = 0; j < 16; ++j) cacc[j] = 0.f;

    uint4 eA0 = ep0[0], eA1 = ep0[16];

    #pragma unroll
    for (int mi = 0; mi < 4; ++mi) {
        uint4 eB0 = {0,0,0,0}, eB1 = {0,0,0,0};
        if (mi < 3) { eB0 = ep0[(mi + 1) * 128]; eB1 = ep0[(mi + 1) * 128 + 16]; }

        float fe[16];
        bf8x(eA0, fe); bf8x(eA1, fe + 8);
        float pp = 0.f;
        #pragma unroll
        for (int j = 0; j < 16; ++j)
            pp += vv[j] * ftanh(fe[j] + dfv[j] + cvv[mi] * wcv[j]);
        pp += __shfl_xor(pp, 1);
        pp += __shfl_xor(pp, 2);
        pp += __shfl_xor(pp, 4);
        pp += __shfl_xor(pp, 8);
        const int l = l0 + mi * 4 + lsub;
        if (hc == 0) e_cur[b * LL + l] = pp;

        const float w = fexp(pp) * mskv[mi];   // bounded e -> no max shift
        s += w;
        #pragma unroll
        for (int j = 0; j < 16; ++j) cacc[j] += w * fe[j];
        eA0 = eB0; eA1 = eB1;
    }

    #pragma unroll
    for (int off = 16; off <= 32; off <<= 1) {
        s += __shfl_xor(s, off);
        #pragma unroll
        for (int j = 0; j < 16; ++j) cacc[j] += __shfl_xor(cacc[j], off);
    }

    __shared__ float lsum[4];
    __shared__ float lctx[4][HH];
    if (lsub == 0) {
        #pragma unroll
        for (int k = 0; k < 2; ++k)
            #pragma unroll
            for (int j = 0; j < 8; ++j)
                lctx[wave][hc * 8 + 128 * k + j] = cacc[k * 8 + j];
    }
    if (lane == 0) lsum[wave] = s;
    __syncthreads();

    // relaxed atomic accumulation at the coherence point (no L2 flush)
    atomicAdd(&ctx_acc[((size_t)t * BB + b) * HH + tid],
              lctx[0][tid] + lctx[1][tid] + lctx[2][tid] + lctx[3][tid]);
    if (tid == 0)
        atomicAdd(&S_acc[t * BB + b], lsum[0] + lsum[1] + lsum[2] + lsum[3]);

    // ---- 4-winner election ----
    __shared__ int s_rank;
    __syncthreads();   // drain partial atomics before counting
    if (tid == 0) {
        const int old = atomicAdd(&cnt[t * BB + b], 1);
        s_rank = old - (NCHUNK - 4);    // >=0 for the last 4 blocks
        if (s_rank >= 0) {
            // wait until ALL 32 blocks' partials are in
            while (atomicAdd(&cnt[t * BB + b], 0) < NCHUNK)
                __builtin_amdgcn_s_sleep(8);
        }
    }
    __syncthreads();
    const int sl = s_rank;
    if (sl < 0) return;
    const int us = sl * 64;

    // ================= tail slice sl (4 blocks per batch) ==================
    __shared__ float t_sctx[HH];
    __shared__ float t_sxh[EE + HH];
    __shared__ float t_red[256];
    __shared__ float t_zs[256];
    __shared__ float t_scl[64], t_shl[64];
    __shared__ float t_S;

    // 1. ctx(t): coherent reads of accumulators
    {
        const float cs = atomicAdd(&ctx_acc[((size_t)t * BB + b) * HH + tid], 0.f);
        if (tid == 0) t_S = atomicAdd(&S_acc[t * BB + b], 0.f);
        __syncthreads();
        const float invS = 1.f / t_S;
        const float cx = cs * invS;
        t_sctx[tid] = cx;
        if (sl == 3) {
            ctx_hist[((size_t)t * BB + b) * HH + tid] = cx;
            if (tid == 0) is_ws[b] = invS;
        }
        t_sxh[EE + tid] = h_hist[((size_t)t * BB + b) * HH + tid];
    }
    __syncthreads();

    if (t + 1 >= T_STEPS) return;

    // 2. x(t+1) (redundant per slice): 2 threads/col, K=192
    {
        const int j = tid & 127, q = tid >> 7;
        float a = 0.f;
        #pragma unroll 8
        for (int r = q * 192; r < q * 192 + 192; ++r) {
            const float f = (r < EE) ? dec_in[((size_t)(t + 1) * BB + b) * EE + r]
                                     : t_sctx[r - EE];
            a += f * Wx[(size_t)r * EE + j];
        }
        t_red[tid] = a;
    }
    __syncthreads();
    if (tid < EE) {
        const float xv = fmaxf(t_red[tid] + t_red[128 + tid] + bx[tid], 0.f);
        t_sxh[tid] = xv;
        if (sl == 3) x_hist[((size_t)(t + 1) * BB + b) * EE + tid] = xv;
    }
    __syncthreads();

    // 3. z-slice: thread = (gate g = tid>>6, unit uo = tid&63), K=384
    {
        const int gg = tid >> 6, uo = tid & 63;
        const int zcol = gg * 256 + us + uo;
        float z = bl[zcol];
        const float* w = Wl + zcol;
        #pragma unroll 4
        for (int r = 0; r < EE + HH; ++r)
            z += t_sxh[r] * w[(size_t)r * 1024];
        t_zs[tid] = z;
    }
    __syncthreads();

    // 4. c,h for the slice's 64 units
    if (tid < 64) {
        const int u = us + tid;
        const float zi = t_zs[tid], zf = t_zs[64 + tid],
                    zg = t_zs[128 + tid], zo = t_zs[192 + tid];
        const float cp = c_hist[((size_t)t * BB + b) * HH + u];
        const float cn = fsig(zf) * cp + fsig(zi) * ftanh(zg);
        const float hn = fsig(zo) * ftanh(cn);
        c_hist[((size_t)(t + 1) * BB + b) * HH + u] = cn;
        h_hist[((size_t)(t + 1) * BB + b) * HH + u] = hn;
        t_scl[tid] = cn; t_shl[tid] = hn;
    }
    __syncthreads();

    // 5. df_part[sl] for t+1: thread = col j, 128 MACs
    {
        const int j = tid;
        float a = 0.f;
        #pragma unroll 8
        for (int u = 0; u < 64; ++u)
            a += t_scl[u] * Ws[(size_t)(us + u) * HH + j]
               + t_shl[u] * Ws[(size_t)(256 + us + u) * HH + j];
        df_part[((size_t)sl * BB + b) * HH + j] = a;
    }
}

// ---------------------------------------------------------------------------
// K3: epilogue: attns[T-1], final cov, c/h outputs. Grid BB, 256 threads.
// ---------------------------------------------------------------------------
__global__ __launch_bounds__(256) void epi_kernel(
    const float* __restrict__ e_ws, const float* __restrict__ mask,
    const float* __restrict__ is_ws,
    const float* __restrict__ c_hist, const float* __restrict__ h_hist,
    float* __restrict__ attns, float* __restrict__ cov,
    float* __restrict__ c_out, float* __restrict__ h_out)
{
    const int b = blockIdx.x;
    const int j = threadIdx.x;
    const float iS = is_ws[b];
    const float* e_last = e_ws + (size_t)((T_STEPS - 1) & 1) * BB * LL;
    for (int i = 0; i < LL / 256; ++i) {
        const int l = i * 256 + j;
        const int idx = b * LL + l;
        const float a = fexp(e_last[idx]) * mask[idx] * iS;
        attns[((size_t)(T_STEPS - 1) * BB + b) * LL + l] = a;
        cov[idx] += a;
    }
    c_out[b * HH + j] = c_hist[((size_t)(T_STEPS - 1) * BB + b) * HH + j];
    h_out[b * HH + j] = h_hist[((size_t)(T_STEPS - 1) * BB + b) * HH + j];
}

// ---------------------------------------------------------------------------
// K4: batched outs + pgens. Grid 512 blocks = (t, 8-batch slice), 512 thr.
// ---------------------------------------------------------------------------
__global__ __launch_bounds__(512) void out_kernel(
    const float* __restrict__ h_hist, const float* __restrict__ ctx_hist,
    const float* __restrict__ c_hist, const float* __restrict__ x_hist,
    const float* __restrict__ Wo, const float* __restrict__ bo,
    const float* __restrict__ Wp, const float* __restrict__ bp,
    float* __restrict__ outs, float* __restrict__ pgens)
{
    const int t = blockIdx.x >> 3;
    const int b8 = blockIdx.x & 7;
    const int tid = threadIdx.x;
    __shared__ float hs[8 * 256], cts[8 * 256], cs2[8 * 256], xs[8 * 128];
    __shared__ float zbuf[8 * 256];

    for (int i = tid; i < 8 * 256; i += 512) {
        const int bl = i >> 8, j = i & 255;
        const size_t row = ((size_t)t * BB + b8 * 8 + bl) * HH;
        hs[i] = h_hist[row + j];
        cts[i] = ctx_hist[row + j];
        cs2[i] = c_hist[row + j];
    }
    for (int i = tid; i < 8 * 128; i += 512) {
        const int bl = i >> 7, j = i & 127;
        xs[i] = x_hist[((size_t)t * BB + b8 * 8 + bl) * EE + j];
    }
    __syncthreads();

    {
        const int j = tid & 255, rh = tid >> 8;
        float acc[8];
        #pragma unroll
        for (int bl = 0; bl < 8; ++bl) acc[bl] = 0.f;
        const int r0 = rh * 128;
        #pragma unroll 4
        for (int r = r0; r < r0 + 128; ++r) {
            const float w0 = Wo[(size_t)r * HH + j];
            const float w1 = Wo[(size_t)(256 + r) * HH + j];
            #pragma unroll
            for (int bl = 0; bl < 8; ++bl)
                acc[bl] += hs[bl * 256 + r] * w0 + cts[bl * 256 + r] * w1;
        }
        if (rh) {
            #pragma unroll
            for (int bl = 0; bl < 8; ++bl) zbuf[bl * 256 + j] = acc[bl];
        }
        __syncthreads();
        if (!rh) {
            #pragma unroll
            for (int bl = 0; bl < 8; ++bl)
                outs[((size_t)t * BB + b8 * 8 + bl) * HH + j] =
                    acc[bl] + zbuf[bl * 256 + j] + bo[j];
        }
    }

    {
        const int bl = tid >> 6, r64 = tid & 63;
        float pp = 0.f;
        for (int i = r64; i < 256; i += 64)
            pp += cts[bl * 256 + i] * Wp[i] + cs2[bl * 256 + i] * Wp[256 + i]
                + hs[bl * 256 + i] * Wp[512 + i];
        for (int i = r64; i < 128; i += 64)
            pp += xs[bl * 128 + i] * Wp[768 + i];
        #pragma unroll
        for (int off = 32; off; off >>= 1) pp += __shfl_xor(pp, off);
        if (r64 == 0)
            pgens[(size_t)t * BB + b8 * 8 + bl] = fsig(pp + bp[0]);
    }
}

extern "C" void kernel_launch(void* const* d_in, const int* in_sizes, int n_in,
                              void* d_out, int out_size, void* d_ws, size_t ws_size,
                              hipStream_t stream) {
    const float* dec_in = (const float*)d_in[0];
    const float* init_c = (const float*)d_in[1];
    const float* init_h = (const float*)d_in[2];
    const float* enc    = (const float*)d_in[3];
    const float* mask   = (const float*)d_in[4];
    const float* Wx = (const float*)d_in[5];
    const float* bx = (const float*)d_in[6];
    const float* Wl = (const float*)d_in[7];
    const float* bl = (const float*)d_in[8];
    const float* Ws = (const float*)d_in[9];
    const float* bs = (const float*)d_in[10];
    const float* v  = (const float*)d_in[11];
    const float* wc = (const float*)d_in[12];
    const float* Wp = (const float*)d_in[13];
    const float* bp = (const float*)d_in[14];
    const float* Wo = (const float*)d_in[15];
    const float* bo = (const float*)d_in[16];

    float* out   = (float*)d_out;
    float* outs  = out;                                   // T*B*H
    float* c_out = outs + (size_t)T_STEPS * BB * HH;      // B*H
    float* h_out = c_out + BB * HH;                       // B*H
    float* attns = h_out + BB * HH;                       // T*B*L
    float* pgens = attns + (size_t)T_STEPS * BB * LL;     // T*B
    float* cov   = pgens + T_STEPS * BB;                  // B*L

    float* ws     = (float*)d_ws;
    uint4* encb   = (uint4*)ws;                           // B*L*H bf16
    float* w      = ws + (size_t)BB * LL * HH / 2;
    float* e_ws   = w;    w += 2 * BB * LL;
    float* ctx_acc = w;   w += (size_t)T_STEPS * BB * HH; // per-step slots
    float* S_acc  = w;    w += T_STEPS * BB;
    float* x_hist = w;    w += (size_t)T_STEPS * BB * EE;
    float* df_part = w;   w += 4 * BB * HH;
    float* is_ws  = w;    w += BB;
    float* ctx_hist = w;  w += (size_t)T_STEPS * BB * HH;
    float* c_hist = w;    w += (size_t)T_STEPS * BB * HH;
    float* h_hist = w;    w += (size_t)T_STEPS * BB * HH;
    int* cnt      = (int*)w;                              // T*B counters

    conv_kernel<<<4096, 256, 0, stream>>>((const float4*)enc, encb,
        ctx_acc, S_acc, cnt);
    pre_kernel<<<BB, 256, 0, stream>>>(dec_in, init_c, init_h,
        Wx, bx, Wl, bl, Ws, x_hist, c_hist, h_hist, df_part);

    for (int t = 0; t < T_STEPS; ++t) {
        attn_kernel<<<NCHUNK * BB, 256, 0, stream>>>(encb, mask, cov, df_part,
            bs, v, wc, e_ws, attns, is_ws, ctx_acc, S_acc, cnt,
            dec_in, Wx, bx, Wl, bl, Ws,
            ctx_hist, x_hist, c_hist, h_hist, t);
    }
    epi_kernel<<<BB, 256, 0, stream>>>(e_ws, mask, is_ws,
        c_hist, h_hist, attns, cov, c_out, h_out);
    out_kernel<<<512, 512, 0, stream>>>(h_hist, ctx_hist, c_hist, x_hist,
        Wo, bo, Wp, bp, outs, pgens);
}

// Round 18
// 2849.659 us; speedup vs baseline: 2.0916x; 1.6968x over previous
//
#include <hip/hip_runtime.h>
#include <math.h>

#define T_STEPS 64
#define BB 64
#define LL 2048
#define EE 128
#define HH 256
#define NCHUNK 32
#define LCHUNK (LL / NCHUNK) /* 64 */

__device__ __forceinline__ float fexp(float x) {
    return __builtin_amdgcn_exp2f(x * 1.44269504088896340736f);
}
__device__ __forceinline__ float fsig(float x) {
    return __builtin_amdgcn_rcpf(1.f + __builtin_amdgcn_exp2f(-1.44269504088896340736f * x));
}
__device__ __forceinline__ float ftanh(float x) {
    float xc = fminf(fmaxf(x, -20.f), 20.f);
    float p = __builtin_amdgcn_exp2f(2.885390081777926814f * xc); // e^{2x}
    return (p - 1.f) * __builtin_amdgcn_rcpf(p + 1.f);
}
__device__ __forceinline__ unsigned int bfr(float x) {
    unsigned int u = __float_as_uint(x);
    return (u + 0x7FFFu + ((u >> 16) & 1u)) >> 16;
}
__device__ __forceinline__ void bf8x(const uint4 q, float* f) {
    f[0] = __uint_as_float(q.x << 16); f[1] = __uint_as_float(q.x & 0xFFFF0000u);
    f[2] = __uint_as_float(q.y << 16); f[3] = __uint_as_float(q.y & 0xFFFF0000u);
    f[4] = __uint_as_float(q.z << 16); f[5] = __uint_as_float(q.z & 0xFFFF0000u);
    f[6] = __uint_as_float(q.w << 16); f[7] = __uint_as_float(q.w & 0xFFFF0000u);
}
__device__ __forceinline__ void load8(const float* p, float* d) {
    float4 a = *(const float4*)p, b = *(const float4*)(p + 4);
    d[0]=a.x; d[1]=a.y; d[2]=a.z; d[3]=a.w; d[4]=b.x; d[5]=b.y; d[6]=b.z; d[7]=b.w;
}

// ---------------------------------------------------------------------------
// K0: one-time fp32 -> bf16 conversion of enc (RNE).
// ---------------------------------------------------------------------------
__global__ __launch_bounds__(256) void conv_kernel(
    const float4* __restrict__ enc, uint4* __restrict__ encb)
{
    const int n = BB * LL * HH / 8;
    for (int i = blockIdx.x * 256 + threadIdx.x; i < n; i += gridDim.x * 256) {
        const float4 a = enc[2 * i], c = enc[2 * i + 1];
        uint4 o;
        o.x = bfr(a.x) | (bfr(a.y) << 16);
        o.y = bfr(a.z) | (bfr(a.w) << 16);
        o.z = bfr(c.x) | (bfr(c.y) << 16);
        o.w = bfr(c.z) | (bfr(c.w) << 16);
        encb[i] = o;
    }
}

// ---------------------------------------------------------------------------
// K1 (fused recurrent step, r12-proven): grid 256 blocks = (s: 4 unit-slices)
// x (b: 64), 512 threads. A ctx-combine (redundant x4, s=0 writes) ->
// B x-GEMM (redundant) -> C z-slice -> D c,h -> E partial dec_feat.
// attn completes df = tanh(sum_s df_part + bs). t==T_STEPS: combine only.
// Kernel-boundary coherence only; no cross-block atomics (r17 lesson: the
// relaxed-atomic election races under graph replay).
// ---------------------------------------------------------------------------
__global__ __launch_bounds__(512) void step_kernel(
    const float* __restrict__ dec_in,
    const float* __restrict__ init_c, const float* __restrict__ init_h,
    const float* __restrict__ sp, const float* __restrict__ ctxp,
    const float* __restrict__ Wx, const float* __restrict__ bx,
    const float* __restrict__ Wl, const float* __restrict__ bl,
    const float* __restrict__ Ws,
    float* __restrict__ ctx_hist, float* __restrict__ x_hist,
    float* __restrict__ c_hist, float* __restrict__ h_hist,
    float* __restrict__ df_part, float* __restrict__ is_ws, int t)
{
    const int b = blockIdx.x & 63;
    const int s = blockIdx.x >> 6;     // unit-slice 0..3
    const int us = s * 64;
    const int tid = threadIdx.x;
    __shared__ float sctx[HH], siv[EE];
    __shared__ float sxh[EE + HH];     // [x_t, h_prev]
    __shared__ float red[512];
    __shared__ float scl[64], shl[64]; // c_new, h_new for slice units

    const float* hsrc = (t == 0) ? init_h : h_hist + (size_t)(t - 1) * BB * HH;
    const float* csrc = (t == 0) ? init_c : c_hist + (size_t)(t - 1) * BB * HH;

    // ---- A: ctx combine (redundant per slice) + stage h_prev, dec_in ----
    if (tid < HH) {
        if (t > 0) {
            float S = 0.f, cs = 0.f;
            #pragma unroll 8
            for (int k = 0; k < NCHUNK; ++k) {
                S += sp[k * BB + b];
                cs += ctxp[(size_t)(k * BB + b) * HH + tid];
            }
            const float invS = 1.f / S;
            const float cx = cs * invS;
            sctx[tid] = cx;
            if (s == 0) {
                ctx_hist[((size_t)(t - 1) * BB + b) * HH + tid] = cx;
                if (tid == 0) is_ws[b] = invS;
            }
        } else {
            sctx[tid] = 0.f;
        }
    } else {
        const int i = tid - HH;        // 0..255
        sxh[EE + i] = hsrc[(size_t)b * HH + i];
        if (i < EE && t < T_STEPS)
            siv[i] = dec_in[((size_t)t * BB + b) * EE + i];
    }
    __syncthreads();

    if (t >= T_STEPS) return;

    // ---- B: x_t = relu([inp, ctx] @ Wx + bx); 4 threads per output ----
    {
        const int j = tid & 127, q = tid >> 7;
        float a = 0.f;
        #pragma unroll 8
        for (int r = q * 96; r < q * 96 + 96; ++r) {
            const float f = (r < EE) ? siv[r] : sctx[r - EE];
            a += f * Wx[(size_t)r * EE + j];
        }
        red[tid] = a;
    }
    __syncthreads();
    if (tid < EE) {
        const float xv = fmaxf(red[tid] + red[128 + tid] + red[256 + tid]
                               + red[384 + tid] + bx[tid], 0.f);
        sxh[tid] = xv;
        if (s == 0) x_hist[((size_t)t * BB + b) * EE + tid] = xv;
    }
    __syncthreads();

    // ---- C: z-slice; col c = g*64+uo -> zcol = g*256+us+uo; K split 2 ----
    {
        const int c = tid & 255, half = tid >> 8;
        const int zcol = (c >> 6) * 256 + us + (c & 63);
        const float* w = Wl + (size_t)(half * 192) * 1024 + zcol;
        const float* f = sxh + half * 192;
        float a0 = 0.f, a1 = 0.f;
        #pragma unroll 8
        for (int r = 0; r < 96; ++r) {
            a0 += f[r] * w[(size_t)r * 1024];
            a1 += f[r + 96] * w[(size_t)(r + 96) * 1024];
        }
        red[tid] = a0 + a1;
    }
    __syncthreads();

    // ---- D: c,h for slice units ----
    if (tid < 64) {
        const int u = us + tid;
        const float zi = red[tid]       + red[256 + tid] + bl[u];
        const float zf = red[64 + tid]  + red[320 + tid] + bl[256 + u];
        const float zg = red[128 + tid] + red[384 + tid] + bl[512 + u];
        const float zo = red[192 + tid] + red[448 + tid] + bl[768 + u];
        const float cp = csrc[(size_t)b * HH + u];
        const float cn = fsig(zf) * cp + fsig(zi) * ftanh(zg);
        const float hn = fsig(zo) * ftanh(cn);
        c_hist[((size_t)t * BB + b) * HH + u] = cn;
        h_hist[((size_t)t * BB + b) * HH + u] = hn;
        scl[tid] = cn;
        shl[tid] = hn;
    }
    __syncthreads();

    // ---- E: partial dec_feat rows (slice's 64 c-rows + 64 h-rows) ----
    {
        const int j = tid & 255, half = tid >> 8;
        const float* src = half ? shl : scl;
        const int r0 = half ? (256 + us) : us;
        float a = 0.f;
        #pragma unroll 8
        for (int u = 0; u < 64; ++u)
            a += src[u] * Ws[(size_t)(r0 + u) * HH + j];
        red[tid] = a;
    }
    __syncthreads();
    if (tid < HH)
        df_part[((size_t)s * BB + b) * HH + tid] = red[tid] + red[256 + tid];
}

// ---------------------------------------------------------------------------
// K2: attention pass for step t (bf16 enc, depth-1 prefetch — r12-proven;
// r14 showed full prefetch costs ~+2us), fused with step-(t-1) epilogue.
// df completed here: df = tanh(sum_s df_part[s] + bs).
// Grid: NCHUNK*BB = 2048 blocks, 256 threads.
// ---------------------------------------------------------------------------
__global__ __launch_bounds__(256) void attn_kernel(
    const uint4* __restrict__ encb, const float* __restrict__ mask,
    float* __restrict__ cov, const float* __restrict__ df_part,
    const float* __restrict__ bs,
    const float* __restrict__ v, const float* __restrict__ wc,
    float* __restrict__ e_ws, float* __restrict__ attns,
    const float* __restrict__ is_ws,
    float* __restrict__ sp, float* __restrict__ ctxp, int t)
{
    const int prev_t = t - 1;
    const int g = blockIdx.x;
    const int b = g & (BB - 1);
    const int chunk = g >> 6;
    const int tid = threadIdx.x;
    const int wave = tid >> 6;
    const int lane = tid & 63;
    const int hc = lane & 15;
    const int lsub = lane >> 4;
    const int l0 = chunk * LCHUNK + wave * (LCHUNK / 4);

    const float* e_prev = e_ws + (size_t)(prev_t & 1) * BB * LL;
    float* e_cur = e_ws + (size_t)(t & 1) * BB * LL;
    const float iSprev = (prev_t >= 0) ? is_ws[b] : 0.f;

    float mskv[4], covv[4], epv[4];
    #pragma unroll
    for (int mi = 0; mi < 4; ++mi) {
        const int idx = b * LL + l0 + mi * 4 + lsub;
        mskv[mi] = mask[idx];
        covv[mi] = (prev_t >= 0) ? cov[idx] : 0.f;
        epv[mi]  = (prev_t >= 0) ? e_prev[idx] : 0.f;
    }

    // complete dec_feat: df = tanh(sum_s df_part + bs)
    float dfv[16], vv[16], wcv[16];
    #pragma unroll
    for (int k = 0; k < 2; ++k) {
        const int h = hc * 8 + 128 * k;
        float d0[8], d1[8], d2[8], d3[8], bsv[8];
        load8(df_part + (size_t)(0 * BB + b) * HH + h, d0);
        load8(df_part + (size_t)(1 * BB + b) * HH + h, d1);
        load8(df_part + (size_t)(2 * BB + b) * HH + h, d2);
        load8(df_part + (size_t)(3 * BB + b) * HH + h, d3);
        load8(bs + h, bsv);
        #pragma unroll
        for (int j = 0; j < 8; ++j)
            dfv[8 * k + j] = ftanh(d0[j] + d1[j] + d2[j] + d3[j] + bsv[j]);
        load8(v + h, vv + 8 * k);
        load8(wc + h, wcv + 8 * k);
    }

    float cvv[4];
    #pragma unroll
    for (int mi = 0; mi < 4; ++mi) {
        const int l = l0 + mi * 4 + lsub;
        const int idx = b * LL + l;
        if (prev_t >= 0) {
            const float a = fexp(epv[mi]) * mskv[mi] * iSprev;
            cvv[mi] = covv[mi] + a;
            if (hc == 0) {
                cov[idx] = cvv[mi];
                attns[((size_t)prev_t * BB + b) * LL + l] = a;
            }
        } else {
            cvv[mi] = 0.f;
            if (hc == 0) cov[idx] = 0.f;
        }
    }

    const uint4* ep0 = encb + (size_t)(b * LL + l0 + lsub) * 32 + hc;

    float s = 0.f;
    float cacc[16];
    #pragma unroll
    for (int j = 0; j < 16; ++j) cacc[j] = 0.f;

    uint4 eA0 = ep0[0], eA1 = ep0[16];

    #pragma unroll
    for (int mi = 0; mi < 4; ++mi) {
        uint4 eB0 = {0,0,0,0}, eB1 = {0,0,0,0};
        if (mi < 3) { eB0 = ep0[(mi + 1) * 128]; eB1 = ep0[(mi + 1) * 128 + 16]; }

        float fe[16];
        bf8x(eA0, fe); bf8x(eA1, fe + 8);
        float pp = 0.f;
        #pragma unroll
        for (int j = 0; j < 16; ++j)
            pp += vv[j] * ftanh(fe[j] + dfv[j] + cvv[mi] * wcv[j]);
        pp += __shfl_xor(pp, 1);
        pp += __shfl_xor(pp, 2);
        pp += __shfl_xor(pp, 4);
        pp += __shfl_xor(pp, 8);
        const int l = l0 + mi * 4 + lsub;
        if (hc == 0) e_cur[b * LL + l] = pp;

        const float w = fexp(pp) * mskv[mi];   // bounded e -> no max shift
        s += w;
        #pragma unroll
        for (int j = 0; j < 16; ++j) cacc[j] += w * fe[j];
        eA0 = eB0; eA1 = eB1;
    }

    #pragma unroll
    for (int off = 16; off <= 32; off <<= 1) {
        s += __shfl_xor(s, off);
        #pragma unroll
        for (int j = 0; j < 16; ++j) cacc[j] += __shfl_xor(cacc[j], off);
    }

    __shared__ float lsum[4];
    __shared__ float lctx[4][HH];
    if (lsub == 0) {
        #pragma unroll
        for (int k = 0; k < 2; ++k)
            #pragma unroll
            for (int j = 0; j < 8; ++j)
                lctx[wave][hc * 8 + 128 * k + j] = cacc[k * 8 + j];
    }
    if (lane == 0) lsum[wave] = s;
    __syncthreads();

    const int pidx = chunk * BB + b;
    ctxp[(size_t)pidx * HH + tid] =
        lctx[0][tid] + lctx[1][tid] + lctx[2][tid] + lctx[3][tid];
    if (tid == 0)
        sp[pidx] = lsum[0] + lsum[1] + lsum[2] + lsum[3];
}

// ---------------------------------------------------------------------------
// K3: epilogue: attns[T-1], final cov, c/h outputs. Grid BB, 256 threads.
// ---------------------------------------------------------------------------
__global__ __launch_bounds__(256) void epi_kernel(
    const float* __restrict__ e_ws, const float* __restrict__ mask,
    const float* __restrict__ is_ws,
    const float* __restrict__ c_hist, const float* __restrict__ h_hist,
    float* __restrict__ attns, float* __restrict__ cov,
    float* __restrict__ c_out, float* __restrict__ h_out)
{
    const int b = blockIdx.x;
    const int j = threadIdx.x;
    const float iS = is_ws[b];
    const float* e_last = e_ws + (size_t)((T_STEPS - 1) & 1) * BB * LL;
    for (int i = 0; i < LL / 256; ++i) {
        const int l = i * 256 + j;
        const int idx = b * LL + l;
        const float a = fexp(e_last[idx]) * mask[idx] * iS;
        attns[((size_t)(T_STEPS - 1) * BB + b) * LL + l] = a;
        cov[idx] += a;
    }
    c_out[b * HH + j] = c_hist[((size_t)(T_STEPS - 1) * BB + b) * HH + j];
    h_out[b * HH + j] = h_hist[((size_t)(T_STEPS - 1) * BB + b) * HH + j];
}

// ---------------------------------------------------------------------------
// K4: batched outs + pgens. Grid 512 blocks = (t, 8-batch slice), 512 thr.
// LDS 37 KB -> ~4 blocks/CU (r12's 72 KB version measured 87 us at 22% occ).
// ---------------------------------------------------------------------------
__global__ __launch_bounds__(512) void out_kernel(
    const float* __restrict__ h_hist, const float* __restrict__ ctx_hist,
    const float* __restrict__ c_hist, const float* __restrict__ x_hist,
    const float* __restrict__ Wo, const float* __restrict__ bo,
    const float* __restrict__ Wp, const float* __restrict__ bp,
    float* __restrict__ outs, float* __restrict__ pgens)
{
    const int t = blockIdx.x >> 3;
    const int b8 = blockIdx.x & 7;
    const int tid = threadIdx.x;
    __shared__ float hs[8 * 256], cts[8 * 256], cs2[8 * 256], xs[8 * 128];
    __shared__ float zbuf[8 * 256];

    for (int i = tid; i < 8 * 256; i += 512) {
        const int bl = i >> 8, j = i & 255;
        const size_t row = ((size_t)t * BB + b8 * 8 + bl) * HH;
        hs[i] = h_hist[row + j];
        cts[i] = ctx_hist[row + j];
        cs2[i] = c_hist[row + j];
    }
    for (int i = tid; i < 8 * 128; i += 512) {
        const int bl = i >> 7, j = i & 127;
        xs[i] = x_hist[((size_t)t * BB + b8 * 8 + bl) * EE + j];
    }
    __syncthreads();

    {
        const int j = tid & 255, rh = tid >> 8;
        float acc[8];
        #pragma unroll
        for (int bl = 0; bl < 8; ++bl) acc[bl] = 0.f;
        const int r0 = rh * 128;
        #pragma unroll 4
        for (int r = r0; r < r0 + 128; ++r) {
            const float w0 = Wo[(size_t)r * HH + j];
            const float w1 = Wo[(size_t)(256 + r) * HH + j];
            #pragma unroll
            for (int bl = 0; bl < 8; ++bl)
                acc[bl] += hs[bl * 256 + r] * w0 + cts[bl * 256 + r] * w1;
        }
        if (rh) {
            #pragma unroll
            for (int bl = 0; bl < 8; ++bl) zbuf[bl * 256 + j] = acc[bl];
        }
        __syncthreads();
        if (!rh) {
            #pragma unroll
            for (int bl = 0; bl < 8; ++bl)
                outs[((size_t)t * BB + b8 * 8 + bl) * HH + j] =
                    acc[bl] + zbuf[bl * 256 + j] + bo[j];
        }
    }

    {
        const int bl = tid >> 6, r64 = tid & 63;
        float pp = 0.f;
        for (int i = r64; i < 256; i += 64)
            pp += cts[bl * 256 + i] * Wp[i] + cs2[bl * 256 + i] * Wp[256 + i]
                + hs[bl * 256 + i] * Wp[512 + i];
        for (int i = r64; i < 128; i += 64)
            pp += xs[bl * 128 + i] * Wp[768 + i];
        #pragma unroll
        for (int off = 32; off; off >>= 1) pp += __shfl_xor(pp, off);
        if (r64 == 0)
            pgens[(size_t)t * BB + b8 * 8 + bl] = fsig(pp + bp[0]);
    }
}

extern "C" void kernel_launch(void* const* d_in, const int* in_sizes, int n_in,
                              void* d_out, int out_size, void* d_ws, size_t ws_size,
                              hipStream_t stream) {
    const float* dec_in = (const float*)d_in[0];
    const float* init_c = (const float*)d_in[1];
    const float* init_h = (const float*)d_in[2];
    const float* enc    = (const float*)d_in[3];
    const float* mask   = (const float*)d_in[4];
    const float* Wx = (const float*)d_in[5];
    const float* bx = (const float*)d_in[6];
    const float* Wl = (const float*)d_in[7];
    const float* bl = (const float*)d_in[8];
    const float* Ws = (const float*)d_in[9];
    const float* bs = (const float*)d_in[10];
    const float* v  = (const float*)d_in[11];
    const float* wc = (const float*)d_in[12];
    const float* Wp = (const float*)d_in[13];
    const float* bp = (const float*)d_in[14];
    const float* Wo = (const float*)d_in[15];
    const float* bo = (const float*)d_in[16];

    float* out   = (float*)d_out;
    float* outs  = out;                                   // T*B*H
    float* c_out = outs + (size_t)T_STEPS * BB * HH;      // B*H
    float* h_out = c_out + BB * HH;                       // B*H
    float* attns = h_out + BB * HH;                       // T*B*L
    float* pgens = attns + (size_t)T_STEPS * BB * LL;     // T*B
    float* cov   = pgens + T_STEPS * BB;                  // B*L

    float* ws     = (float*)d_ws;
    uint4* encb   = (uint4*)ws;                           // B*L*H bf16
    float* w      = ws + (size_t)BB * LL * HH / 2;
    float* e_ws   = w;   w += 2 * BB * LL;
    float* sp     = w;   w += NCHUNK * BB;
    float* ctxp   = w;   w += (size_t)NCHUNK * BB * HH;
    float* x_hist = w;   w += (size_t)T_STEPS * BB * EE;
    float* df_part = w;  w += 4 * BB * HH;
    float* is_ws  = w;   w += BB;
    float* ctx_hist = w; w += (size_t)T_STEPS * BB * HH;
    float* c_hist = w;   w += (size_t)T_STEPS * BB * HH;
    float* h_hist = w;   w += (size_t)T_STEPS * BB * HH;

    conv_kernel<<<4096, 256, 0, stream>>>((const float4*)enc, encb);

    for (int t = 0; t < T_STEPS; ++t) {
        step_kernel<<<256, 512, 0, stream>>>(dec_in, init_c, init_h, sp, ctxp,
            Wx, bx, Wl, bl, Ws,
            ctx_hist, x_hist, c_hist, h_hist, df_part, is_ws, t);
        attn_kernel<<<NCHUNK * BB, 256, 0, stream>>>(encb, mask, cov, df_part,
            bs, v, wc, e_ws, attns, is_ws, sp, ctxp, t);
    }
    step_kernel<<<256, 512, 0, stream>>>(dec_in, init_c, init_h, sp, ctxp,
        Wx, bx, Wl, bl, Ws,
        ctx_hist, x_hist, c_hist, h_hist, df_part, is_ws, T_STEPS);
    epi_kernel<<<BB, 256, 0, stream>>>(e_ws, mask, is_ws,
        c_hist, h_hist, attns, cov, c_out, h_out);
    out_kernel<<<512, 512, 0, stream>>>(h_hist, ctx_hist, c_hist, x_hist,
        Wo, bo, Wp, bp, outs, pgens);
}

// Round 19
// 2710.763 us; speedup vs baseline: 2.1987x; 1.0512x over previous
//
#include <hip/hip_runtime.h>
#include <math.h>

#define T_STEPS 64
#define BB 64
#define LL 2048
#define EE 128
#define HH 256
#define NCHUNK 16
#define LCHUNK (LL / NCHUNK) /* 128 */

__device__ __forceinline__ float fexp(float x) {
    return __builtin_amdgcn_exp2f(x * 1.44269504088896340736f);
}
__device__ __forceinline__ float fsig(float x) {
    return __builtin_amdgcn_rcpf(1.f + __builtin_amdgcn_exp2f(-1.44269504088896340736f * x));
}
__device__ __forceinline__ float ftanh(float x) {
    float xc = fminf(fmaxf(x, -20.f), 20.f);
    float p = __builtin_amdgcn_exp2f(2.885390081777926814f * xc); // e^{2x}
    return (p - 1.f) * __builtin_amdgcn_rcpf(p + 1.f);
}
__device__ __forceinline__ unsigned int bfr(float x) {
    unsigned int u = __float_as_uint(x);
    return (u + 0x7FFFu + ((u >> 16) & 1u)) >> 16;
}
__device__ __forceinline__ void bf8x(const uint4 q, float* f) {
    f[0] = __uint_as_float(q.x << 16); f[1] = __uint_as_float(q.x & 0xFFFF0000u);
    f[2] = __uint_as_float(q.y << 16); f[3] = __uint_as_float(q.y & 0xFFFF0000u);
    f[4] = __uint_as_float(q.z << 16); f[5] = __uint_as_float(q.z & 0xFFFF0000u);
    f[6] = __uint_as_float(q.w << 16); f[7] = __uint_as_float(q.w & 0xFFFF0000u);
}
__device__ __forceinline__ void load8(const float* p, float* d) {
    float4 a = *(const float4*)p, b = *(const float4*)(p + 4);
    d[0]=a.x; d[1]=a.y; d[2]=a.z; d[3]=a.w; d[4]=b.x; d[5]=b.y; d[6]=b.z; d[7]=b.w;
}

// ---------------------------------------------------------------------------
// K0: one-time fp32 -> bf16 conversion of enc (RNE).
// ---------------------------------------------------------------------------
__global__ __launch_bounds__(256) void conv_kernel(
    const float4* __restrict__ enc, uint4* __restrict__ encb)
{
    const int n = BB * LL * HH / 8;
    for (int i = blockIdx.x * 256 + threadIdx.x; i < n; i += gridDim.x * 256) {
        const float4 a = enc[2 * i], c = enc[2 * i + 1];
        uint4 o;
        o.x = bfr(a.x) | (bfr(a.y) << 16);
        o.y = bfr(a.z) | (bfr(a.w) << 16);
        o.z = bfr(c.x) | (bfr(c.y) << 16);
        o.w = bfr(c.z) | (bfr(c.w) << 16);
        encb[i] = o;
    }
}

// ---------------------------------------------------------------------------
// K1 (fused recurrent step, r12-proven shape): grid 256 blocks = (s: 4
// unit-slices) x (b: 64), 512 threads. A ctx-combine (16 partials, redundant
// x4, s=0 writes) -> B x-GEMM (redundant) -> C z-slice -> D c,h -> E partial
// dec_feat. attn completes df = tanh(sum_s df_part + bs).
// t==T_STEPS: combine only. Kernel-boundary coherence only.
// ---------------------------------------------------------------------------
__global__ __launch_bounds__(512) void step_kernel(
    const float* __restrict__ dec_in,
    const float* __restrict__ init_c, const float* __restrict__ init_h,
    const float* __restrict__ sp, const float* __restrict__ ctxp,
    const float* __restrict__ Wx, const float* __restrict__ bx,
    const float* __restrict__ Wl, const float* __restrict__ bl,
    const float* __restrict__ Ws,
    float* __restrict__ ctx_hist, float* __restrict__ x_hist,
    float* __restrict__ c_hist, float* __restrict__ h_hist,
    float* __restrict__ df_part, float* __restrict__ is_ws, int t)
{
    const int b = blockIdx.x & 63;
    const int s = blockIdx.x >> 6;     // unit-slice 0..3
    const int us = s * 64;
    const int tid = threadIdx.x;
    __shared__ float sctx[HH], siv[EE];
    __shared__ float sxh[EE + HH];     // [x_t, h_prev]
    __shared__ float red[512];
    __shared__ float scl[64], shl[64]; // c_new, h_new for slice units

    const float* hsrc = (t == 0) ? init_h : h_hist + (size_t)(t - 1) * BB * HH;
    const float* csrc = (t == 0) ? init_c : c_hist + (size_t)(t - 1) * BB * HH;

    // ---- A: ctx combine (redundant per slice) + stage h_prev, dec_in ----
    if (tid < HH) {
        if (t > 0) {
            float S = 0.f, cs = 0.f;
            #pragma unroll 8
            for (int k = 0; k < NCHUNK; ++k) {
                S += sp[k * BB + b];
                cs += ctxp[(size_t)(k * BB + b) * HH + tid];
            }
            const float invS = 1.f / S;
            const float cx = cs * invS;
            sctx[tid] = cx;
            if (s == 0) {
                ctx_hist[((size_t)(t - 1) * BB + b) * HH + tid] = cx;
                if (tid == 0) is_ws[b] = invS;
            }
        } else {
            sctx[tid] = 0.f;
        }
    } else {
        const int i = tid - HH;        // 0..255
        sxh[EE + i] = hsrc[(size_t)b * HH + i];
        if (i < EE && t < T_STEPS)
            siv[i] = dec_in[((size_t)t * BB + b) * EE + i];
    }
    __syncthreads();

    if (t >= T_STEPS) return;

    // ---- B: x_t = relu([inp, ctx] @ Wx + bx); 4 threads per output ----
    {
        const int j = tid & 127, q = tid >> 7;
        float a = 0.f;
        #pragma unroll 8
        for (int r = q * 96; r < q * 96 + 96; ++r) {
            const float f = (r < EE) ? siv[r] : sctx[r - EE];
            a += f * Wx[(size_t)r * EE + j];
        }
        red[tid] = a;
    }
    __syncthreads();
    if (tid < EE) {
        const float xv = fmaxf(red[tid] + red[128 + tid] + red[256 + tid]
                               + red[384 + tid] + bx[tid], 0.f);
        sxh[tid] = xv;
        if (s == 0) x_hist[((size_t)t * BB + b) * EE + tid] = xv;
    }
    __syncthreads();

    // ---- C: z-slice; col c = g*64+uo -> zcol = g*256+us+uo; K split 2 ----
    {
        const int c = tid & 255, half = tid >> 8;
        const int zcol = (c >> 6) * 256 + us + (c & 63);
        const float* w = Wl + (size_t)(half * 192) * 1024 + zcol;
        const float* f = sxh + half * 192;
        float a0 = 0.f, a1 = 0.f;
        #pragma unroll 8
        for (int r = 0; r < 96; ++r) {
            a0 += f[r] * w[(size_t)r * 1024];
            a1 += f[r + 96] * w[(size_t)(r + 96) * 1024];
        }
        red[tid] = a0 + a1;
    }
    __syncthreads();

    // ---- D: c,h for slice units ----
    if (tid < 64) {
        const int u = us + tid;
        const float zi = red[tid]       + red[256 + tid] + bl[u];
        const float zf = red[64 + tid]  + red[320 + tid] + bl[256 + u];
        const float zg = red[128 + tid] + red[384 + tid] + bl[512 + u];
        const float zo = red[192 + tid] + red[448 + tid] + bl[768 + u];
        const float cp = csrc[(size_t)b * HH + u];
        const float cn = fsig(zf) * cp + fsig(zi) * ftanh(zg);
        const float hn = fsig(zo) * ftanh(cn);
        c_hist[((size_t)t * BB + b) * HH + u] = cn;
        h_hist[((size_t)t * BB + b) * HH + u] = hn;
        scl[tid] = cn;
        shl[tid] = hn;
    }
    __syncthreads();

    // ---- E: partial dec_feat rows (slice's 64 c-rows + 64 h-rows) ----
    {
        const int j = tid & 255, half = tid >> 8;
        const float* src = half ? shl : scl;
        const int r0 = half ? (256 + us) : us;
        float a = 0.f;
        #pragma unroll 8
        for (int u = 0; u < 64; ++u)
            a += src[u] * Ws[(size_t)(r0 + u) * HH + j];
        red[tid] = a;
    }
    __syncthreads();
    if (tid < HH)
        df_part[((size_t)s * BB + b) * HH + tid] = red[tid] + red[256 + tid];
}

// ---------------------------------------------------------------------------
// K2: attention pass for step t (bf16 enc, depth-1 prefetch), fused with
// step-(t-1) epilogue. df completed here: df = tanh(sum_s df_part[s] + bs).
// NCHUNK=16: grid 1024 blocks (all co-resident in one occupancy wave),
// 8 macro-iterations per lane (runtime loop keeps VGPR in check).
// ---------------------------------------------------------------------------
__global__ __launch_bounds__(256) void attn_kernel(
    const uint4* __restrict__ encb, const float* __restrict__ mask,
    float* __restrict__ cov, const float* __restrict__ df_part,
    const float* __restrict__ bs,
    const float* __restrict__ v, const float* __restrict__ wc,
    float* __restrict__ e_ws, float* __restrict__ attns,
    const float* __restrict__ is_ws,
    float* __restrict__ sp, float* __restrict__ ctxp, int t)
{
    const int prev_t = t - 1;
    const int g = blockIdx.x;
    const int b = g & (BB - 1);
    const int chunk = g >> 6;
    const int tid = threadIdx.x;
    const int wave = tid >> 6;
    const int lane = tid & 63;
    const int hc = lane & 15;
    const int lsub = lane >> 4;
    const int l0 = chunk * LCHUNK + wave * (LCHUNK / 4);

    const float* e_prev = e_ws + (size_t)(prev_t & 1) * BB * LL;
    float* e_cur = e_ws + (size_t)(t & 1) * BB * LL;
    const float iSprev = (prev_t >= 0) ? is_ws[b] : 0.f;

    // complete dec_feat: df = tanh(sum_s df_part + bs)
    float dfv[16], vv[16], wcv[16];
    #pragma unroll
    for (int k = 0; k < 2; ++k) {
        const int h = hc * 8 + 128 * k;
        float d0[8], d1[8], d2[8], d3[8], bsv[8];
        load8(df_part + (size_t)(0 * BB + b) * HH + h, d0);
        load8(df_part + (size_t)(1 * BB + b) * HH + h, d1);
        load8(df_part + (size_t)(2 * BB + b) * HH + h, d2);
        load8(df_part + (size_t)(3 * BB + b) * HH + h, d3);
        load8(bs + h, bsv);
        #pragma unroll
        for (int j = 0; j < 8; ++j)
            dfv[8 * k + j] = ftanh(d0[j] + d1[j] + d2[j] + d3[j] + bsv[j]);
        load8(v + h, vv + 8 * k);
        load8(wc + h, wcv + 8 * k);
    }

    const uint4* ep0 = encb + (size_t)(b * LL + l0 + lsub) * 32 + hc;

    float s = 0.f;
    float cacc[16];
    #pragma unroll
    for (int j = 0; j < 16; ++j) cacc[j] = 0.f;

    // depth-1 software pipeline over 8 macro-iterations (4 rows each)
    auto scal = [&](int mi, float& cv, float& msk) {
        const int l = l0 + mi * 4 + lsub;
        const int idx = b * LL + l;
        msk = mask[idx];
        if (prev_t >= 0) {
            const float a = fexp(e_prev[idx]) * msk * iSprev;
            cv = cov[idx] + a;
            if (hc == 0) {
                cov[idx] = cv;
                attns[((size_t)prev_t * BB + b) * LL + l] = a;
            }
        } else {
            cv = 0.f;
            if (hc == 0) cov[idx] = 0.f;
        }
    };

    float cvA, mskA;
    scal(0, cvA, mskA);
    uint4 eA0 = ep0[0], eA1 = ep0[16];

    for (int mi = 0; mi < LCHUNK / 16; ++mi) {   // 8 iterations
        float cvB = 0.f, mskB = 0.f;
        uint4 eB0 = {0,0,0,0}, eB1 = {0,0,0,0};
        if (mi < LCHUNK / 16 - 1) {
            scal(mi + 1, cvB, mskB);
            const uint4* epn = ep0 + (mi + 1) * 128;
            eB0 = epn[0]; eB1 = epn[16];
        }

        float fe[16];
        bf8x(eA0, fe); bf8x(eA1, fe + 8);
        float pp = 0.f;
        #pragma unroll
        for (int j = 0; j < 16; ++j)
            pp += vv[j] * ftanh(fe[j] + dfv[j] + cvA * wcv[j]);
        pp += __shfl_xor(pp, 1);
        pp += __shfl_xor(pp, 2);
        pp += __shfl_xor(pp, 4);
        pp += __shfl_xor(pp, 8);
        const int l = l0 + mi * 4 + lsub;
        if (hc == 0) e_cur[b * LL + l] = pp;

        const float w = fexp(pp) * mskA;   // bounded e -> no max shift
        s += w;
        #pragma unroll
        for (int j = 0; j < 16; ++j) cacc[j] += w * fe[j];
        cvA = cvB; mskA = mskB; eA0 = eB0; eA1 = eB1;
    }

    #pragma unroll
    for (int off = 16; off <= 32; off <<= 1) {
        s += __shfl_xor(s, off);
        #pragma unroll
        for (int j = 0; j < 16; ++j) cacc[j] += __shfl_xor(cacc[j], off);
    }

    __shared__ float lsum[4];
    __shared__ float lctx[4][HH];
    if (lsub == 0) {
        #pragma unroll
        for (int k = 0; k < 2; ++k)
            #pragma unroll
            for (int j = 0; j < 8; ++j)
                lctx[wave][hc * 8 + 128 * k + j] = cacc[k * 8 + j];
    }
    if (lane == 0) lsum[wave] = s;
    __syncthreads();

    const int pidx = chunk * BB + b;
    ctxp[(size_t)pidx * HH + tid] =
        lctx[0][tid] + lctx[1][tid] + lctx[2][tid] + lctx[3][tid];
    if (tid == 0)
        sp[pidx] = lsum[0] + lsum[1] + lsum[2] + lsum[3];
}

// ---------------------------------------------------------------------------
// K3: batched outs + pgens + (for t==T-1 blocks) the final epilogue
// (attns[T-1], cov, c_out/h_out — reusing the staged hs/cs2 tiles).
// Grid 512 blocks = (t, 8-batch slice), 512 threads, LDS 37 KB.
// ---------------------------------------------------------------------------
__global__ __launch_bounds__(512) void out_kernel(
    const float* __restrict__ h_hist, const float* __restrict__ ctx_hist,
    const float* __restrict__ c_hist, const float* __restrict__ x_hist,
    const float* __restrict__ Wo, const float* __restrict__ bo,
    const float* __restrict__ Wp, const float* __restrict__ bp,
    const float* __restrict__ e_ws, const float* __restrict__ mask,
    const float* __restrict__ is_ws,
    float* __restrict__ outs, float* __restrict__ pgens,
    float* __restrict__ attns, float* __restrict__ cov,
    float* __restrict__ c_out, float* __restrict__ h_out)
{
    const int t = blockIdx.x >> 3;
    const int b8 = blockIdx.x & 7;
    const int tid = threadIdx.x;
    __shared__ float hs[8 * 256], cts[8 * 256], cs2[8 * 256], xs[8 * 128];
    __shared__ float zbuf[8 * 256];

    for (int i = tid; i < 8 * 256; i += 512) {
        const int bl = i >> 8, j = i & 255;
        const size_t row = ((size_t)t * BB + b8 * 8 + bl) * HH;
        hs[i] = h_hist[row + j];
        cts[i] = ctx_hist[row + j];
        cs2[i] = c_hist[row + j];
    }
    for (int i = tid; i < 8 * 128; i += 512) {
        const int bl = i >> 7, j = i & 127;
        xs[i] = x_hist[((size_t)t * BB + b8 * 8 + bl) * EE + j];
    }
    __syncthreads();

    {
        const int j = tid & 255, rh = tid >> 8;
        float acc[8];
        #pragma unroll
        for (int bl = 0; bl < 8; ++bl) acc[bl] = 0.f;
        const int r0 = rh * 128;
        #pragma unroll 4
        for (int r = r0; r < r0 + 128; ++r) {
            const float w0 = Wo[(size_t)r * HH + j];
            const float w1 = Wo[(size_t)(256 + r) * HH + j];
            #pragma unroll
            for (int bl = 0; bl < 8; ++bl)
                acc[bl] += hs[bl * 256 + r] * w0 + cts[bl * 256 + r] * w1;
        }
        if (rh) {
            #pragma unroll
            for (int bl = 0; bl < 8; ++bl) zbuf[bl * 256 + j] = acc[bl];
        }
        __syncthreads();
        if (!rh) {
            #pragma unroll
            for (int bl = 0; bl < 8; ++bl)
                outs[((size_t)t * BB + b8 * 8 + bl) * HH + j] =
                    acc[bl] + zbuf[bl * 256 + j] + bo[j];
        }
    }

    {
        const int bl = tid >> 6, r64 = tid & 63;
        float pp = 0.f;
        for (int i = r64; i < 256; i += 64)
            pp += cts[bl * 256 + i] * Wp[i] + cs2[bl * 256 + i] * Wp[256 + i]
                + hs[bl * 256 + i] * Wp[512 + i];
        for (int i = r64; i < 128; i += 64)
            pp += xs[bl * 128 + i] * Wp[768 + i];
        #pragma unroll
        for (int off = 32; off; off >>= 1) pp += __shfl_xor(pp, off);
        if (r64 == 0)
            pgens[(size_t)t * BB + b8 * 8 + bl] = fsig(pp + bp[0]);
    }

    // ---- final-step epilogue (8 blocks): attns[T-1], cov, c/h outputs ----
    if (t == T_STEPS - 1) {
        const float* e_last = e_ws + (size_t)((T_STEPS - 1) & 1) * BB * LL;
        for (int bl = 0; bl < 8; ++bl) {
            const int b = b8 * 8 + bl;
            const float iS = is_ws[b];
            for (int i = tid; i < LL; i += 512) {
                const int idx = b * LL + i;
                const float a = fexp(e_last[idx]) * mask[idx] * iS;
                attns[((size_t)(T_STEPS - 1) * BB + b) * LL + i] = a;
                cov[idx] += a;
            }
        }
        for (int i = tid; i < 8 * HH; i += 512) {
            const int bl = i >> 8, j = i & 255;
            const int b = b8 * 8 + bl;
            c_out[(size_t)b * HH + j] = cs2[bl * 256 + j];
            h_out[(size_t)b * HH + j] = hs[bl * 256 + j];
        }
    }
}

extern "C" void kernel_launch(void* const* d_in, const int* in_sizes, int n_in,
                              void* d_out, int out_size, void* d_ws, size_t ws_size,
                              hipStream_t stream) {
    const float* dec_in = (const float*)d_in[0];
    const float* init_c = (const float*)d_in[1];
    const float* init_h = (const float*)d_in[2];
    const float* enc    = (const float*)d_in[3];
    const float* mask   = (const float*)d_in[4];
    const float* Wx = (const float*)d_in[5];
    const float* bx = (const float*)d_in[6];
    const float* Wl = (const float*)d_in[7];
    const float* bl = (const float*)d_in[8];
    const float* Ws = (const float*)d_in[9];
    const float* bs = (const float*)d_in[10];
    const float* v  = (const float*)d_in[11];
    const float* wc = (const float*)d_in[12];
    const float* Wp = (const float*)d_in[13];
    const float* bp = (const float*)d_in[14];
    const float* Wo = (const float*)d_in[15];
    const float* bo = (const float*)d_in[16];

    float* out   = (float*)d_out;
    float* outs  = out;                                   // T*B*H
    float* c_out = outs + (size_t)T_STEPS * BB * HH;      // B*H
    float* h_out = c_out + BB * HH;                       // B*H
    float* attns = h_out + BB * HH;                       // T*B*L
    float* pgens = attns + (size_t)T_STEPS * BB * LL;     // T*B
    float* cov   = pgens + T_STEPS * BB;                  // B*L

    float* ws     = (float*)d_ws;
    uint4* encb   = (uint4*)ws;                           // B*L*H bf16
    float* w      = ws + (size_t)BB * LL * HH / 2;
    float* e_ws   = w;   w += 2 * BB * LL;
    float* sp     = w;   w += NCHUNK * BB;
    float* ctxp   = w;   w += (size_t)NCHUNK * BB * HH;
    float* x_hist = w;   w += (size_t)T_STEPS * BB * EE;
    float* df_part = w;  w += 4 * BB * HH;
    float* is_ws  = w;   w += BB;
    float* ctx_hist = w; w += (size_t)T_STEPS * BB * HH;
    float* c_hist = w;   w += (size_t)T_STEPS * BB * HH;
    float* h_hist = w;   w += (size_t)T_STEPS * BB * HH;

    conv_kernel<<<4096, 256, 0, stream>>>((const float4*)enc, encb);

    for (int t = 0; t < T_STEPS; ++t) {
        step_kernel<<<256, 512, 0, stream>>>(dec_in, init_c, init_h, sp, ctxp,
            Wx, bx, Wl, bl, Ws,
            ctx_hist, x_hist, c_hist, h_hist, df_part, is_ws, t);
        attn_kernel<<<NCHUNK * BB, 256, 0, stream>>>(encb, mask, cov, df_part,
            bs, v, wc, e_ws, attns, is_ws, sp, ctxp, t);
    }
    step_kernel<<<256, 512, 0, stream>>>(dec_in, init_c, init_h, sp, ctxp,
        Wx, bx, Wl, bl, Ws,
        ctx_hist, x_hist, c_hist, h_hist, df_part, is_ws, T_STEPS);
    out_kernel<<<512, 512, 0, stream>>>(h_hist, ctx_hist, c_hist, x_hist,
        Wo, bo, Wp, bp, e_ws, mask, is_ws,
        outs, pgens, attns, cov, c_out, h_out);
}

// Round 20
// 2624.645 us; speedup vs baseline: 2.2709x; 1.0328x over previous
//
#include <hip/hip_runtime.h>
#include <math.h>

#define T_STEPS 64
#define BB 64
#define LL 2048
#define EE 128
#define HH 256
#define NCHUNK 8
#define LCHUNK (LL / NCHUNK) /* 256 */

__device__ __forceinline__ float fexp(float x) {
    return __builtin_amdgcn_exp2f(x * 1.44269504088896340736f);
}
__device__ __forceinline__ float fsig(float x) {
    return __builtin_amdgcn_rcpf(1.f + __builtin_amdgcn_exp2f(-1.44269504088896340736f * x));
}
__device__ __forceinline__ float ftanh(float x) {
    float xc = fminf(fmaxf(x, -20.f), 20.f);
    float p = __builtin_amdgcn_exp2f(2.885390081777926814f * xc); // e^{2x}
    return (p - 1.f) * __builtin_amdgcn_rcpf(p + 1.f);
}
__device__ __forceinline__ unsigned int bfr(float x) {
    unsigned int u = __float_as_uint(x);
    return (u + 0x7FFFu + ((u >> 16) & 1u)) >> 16;
}
__device__ __forceinline__ void bf8x(const uint4 q, float* f) {
    f[0] = __uint_as_float(q.x << 16); f[1] = __uint_as_float(q.x & 0xFFFF0000u);
    f[2] = __uint_as_float(q.y << 16); f[3] = __uint_as_float(q.y & 0xFFFF0000u);
    f[4] = __uint_as_float(q.z << 16); f[5] = __uint_as_float(q.z & 0xFFFF0000u);
    f[6] = __uint_as_float(q.w << 16); f[7] = __uint_as_float(q.w & 0xFFFF0000u);
}
__device__ __forceinline__ void load8(const float* p, float* d) {
    float4 a = *(const float4*)p, b = *(const float4*)(p + 4);
    d[0]=a.x; d[1]=a.y; d[2]=a.z; d[3]=a.w; d[4]=b.x; d[5]=b.y; d[6]=b.z; d[7]=b.w;
}

// ---------------------------------------------------------------------------
// K0: one-time fp32 -> bf16 conversion of enc (RNE).
// ---------------------------------------------------------------------------
__global__ __launch_bounds__(256) void conv_kernel(
    const float4* __restrict__ enc, uint4* __restrict__ encb)
{
    const int n = BB * LL * HH / 8;
    for (int i = blockIdx.x * 256 + threadIdx.x; i < n; i += gridDim.x * 256) {
        const float4 a = enc[2 * i], c = enc[2 * i + 1];
        uint4 o;
        o.x = bfr(a.x) | (bfr(a.y) << 16);
        o.y = bfr(a.z) | (bfr(a.w) << 16);
        o.z = bfr(c.x) | (bfr(c.y) << 16);
        o.w = bfr(c.z) | (bfr(c.w) << 16);
        encb[i] = o;
    }
}

// ---------------------------------------------------------------------------
// K1 (fused recurrent step, r12-proven shape): grid 256 blocks = (s: 4
// unit-slices) x (b: 64), 512 threads. A ctx-combine (8 partials, redundant
// x4, s=0 writes) -> B x-GEMM (redundant) -> C z-slice -> D c,h -> E partial
// dec_feat. attn completes df = tanh(sum_s df_part + bs).
// t==T_STEPS: combine only. Kernel-boundary coherence only.
// ---------------------------------------------------------------------------
__global__ __launch_bounds__(512) void step_kernel(
    const float* __restrict__ dec_in,
    const float* __restrict__ init_c, const float* __restrict__ init_h,
    const float* __restrict__ sp, const float* __restrict__ ctxp,
    const float* __restrict__ Wx, const float* __restrict__ bx,
    const float* __restrict__ Wl, const float* __restrict__ bl,
    const float* __restrict__ Ws,
    float* __restrict__ ctx_hist, float* __restrict__ x_hist,
    float* __restrict__ c_hist, float* __restrict__ h_hist,
    float* __restrict__ df_part, float* __restrict__ is_ws, int t)
{
    const int b = blockIdx.x & 63;
    const int s = blockIdx.x >> 6;     // unit-slice 0..3
    const int us = s * 64;
    const int tid = threadIdx.x;
    __shared__ float sctx[HH], siv[EE];
    __shared__ float sxh[EE + HH];     // [x_t, h_prev]
    __shared__ float red[512];
    __shared__ float scl[64], shl[64]; // c_new, h_new for slice units

    const float* hsrc = (t == 0) ? init_h : h_hist + (size_t)(t - 1) * BB * HH;
    const float* csrc = (t == 0) ? init_c : c_hist + (size_t)(t - 1) * BB * HH;

    // ---- A: ctx combine (redundant per slice) + stage h_prev, dec_in ----
    if (tid < HH) {
        if (t > 0) {
            float S = 0.f, cs = 0.f;
            #pragma unroll 8
            for (int k = 0; k < NCHUNK; ++k) {
                S += sp[k * BB + b];
                cs += ctxp[(size_t)(k * BB + b) * HH + tid];
            }
            const float invS = 1.f / S;
            const float cx = cs * invS;
            sctx[tid] = cx;
            if (s == 0) {
                ctx_hist[((size_t)(t - 1) * BB + b) * HH + tid] = cx;
                if (tid == 0) is_ws[b] = invS;
            }
        } else {
            sctx[tid] = 0.f;
        }
    } else {
        const int i = tid - HH;        // 0..255
        sxh[EE + i] = hsrc[(size_t)b * HH + i];
        if (i < EE && t < T_STEPS)
            siv[i] = dec_in[((size_t)t * BB + b) * EE + i];
    }
    __syncthreads();

    if (t >= T_STEPS) return;

    // ---- B: x_t = relu([inp, ctx] @ Wx + bx); 4 threads per output ----
    {
        const int j = tid & 127, q = tid >> 7;
        float a = 0.f;
        #pragma unroll 8
        for (int r = q * 96; r < q * 96 + 96; ++r) {
            const float f = (r < EE) ? siv[r] : sctx[r - EE];
            a += f * Wx[(size_t)r * EE + j];
        }
        red[tid] = a;
    }
    __syncthreads();
    if (tid < EE) {
        const float xv = fmaxf(red[tid] + red[128 + tid] + red[256 + tid]
                               + red[384 + tid] + bx[tid], 0.f);
        sxh[tid] = xv;
        if (s == 0) x_hist[((size_t)t * BB + b) * EE + tid] = xv;
    }
    __syncthreads();

    // ---- C: z-slice; col c = g*64+uo -> zcol = g*256+us+uo; K split 2 ----
    {
        const int c = tid & 255, half = tid >> 8;
        const int zcol = (c >> 6) * 256 + us + (c & 63);
        const float* w = Wl + (size_t)(half * 192) * 1024 + zcol;
        const float* f = sxh + half * 192;
        float a0 = 0.f, a1 = 0.f;
        #pragma unroll 8
        for (int r = 0; r < 96; ++r) {
            a0 += f[r] * w[(size_t)r * 1024];
            a1 += f[r + 96] * w[(size_t)(r + 96) * 1024];
        }
        red[tid] = a0 + a1;
    }
    __syncthreads();

    // ---- D: c,h for slice units ----
    if (tid < 64) {
        const int u = us + tid;
        const float zi = red[tid]       + red[256 + tid] + bl[u];
        const float zf = red[64 + tid]  + red[320 + tid] + bl[256 + u];
        const float zg = red[128 + tid] + red[384 + tid] + bl[512 + u];
        const float zo = red[192 + tid] + red[448 + tid] + bl[768 + u];
        const float cp = csrc[(size_t)b * HH + u];
        const float cn = fsig(zf) * cp + fsig(zi) * ftanh(zg);
        const float hn = fsig(zo) * ftanh(cn);
        c_hist[((size_t)t * BB + b) * HH + u] = cn;
        h_hist[((size_t)t * BB + b) * HH + u] = hn;
        scl[tid] = cn;
        shl[tid] = hn;
    }
    __syncthreads();

    // ---- E: partial dec_feat rows (slice's 64 c-rows + 64 h-rows) ----
    {
        const int j = tid & 255, half = tid >> 8;
        const float* src = half ? shl : scl;
        const int r0 = half ? (256 + us) : us;
        float a = 0.f;
        #pragma unroll 8
        for (int u = 0; u < 64; ++u)
            a += src[u] * Ws[(size_t)(r0 + u) * HH + j];
        red[tid] = a;
    }
    __syncthreads();
    if (tid < HH)
        df_part[((size_t)s * BB + b) * HH + tid] = red[tid] + red[256 + tid];
}

// ---------------------------------------------------------------------------
// K2: attention pass for step t (bf16 enc, depth-1 prefetch), fused with
// step-(t-1) epilogue. df completed here: df = tanh(sum_s df_part[s] + bs).
// NCHUNK=8: grid 512 blocks (2/CU, one scheduling wave), 16 macro-iters/lane.
// ---------------------------------------------------------------------------
__global__ __launch_bounds__(256) void attn_kernel(
    const uint4* __restrict__ encb, const float* __restrict__ mask,
    float* __restrict__ cov, const float* __restrict__ df_part,
    const float* __restrict__ bs,
    const float* __restrict__ v, const float* __restrict__ wc,
    float* __restrict__ e_ws, float* __restrict__ attns,
    const float* __restrict__ is_ws,
    float* __restrict__ sp, float* __restrict__ ctxp, int t)
{
    const int prev_t = t - 1;
    const int g = blockIdx.x;
    const int b = g & (BB - 1);
    const int chunk = g >> 6;
    const int tid = threadIdx.x;
    const int wave = tid >> 6;
    const int lane = tid & 63;
    const int hc = lane & 15;
    const int lsub = lane >> 4;
    const int l0 = chunk * LCHUNK + wave * (LCHUNK / 4);

    const float* e_prev = e_ws + (size_t)(prev_t & 1) * BB * LL;
    float* e_cur = e_ws + (size_t)(t & 1) * BB * LL;
    const float iSprev = (prev_t >= 0) ? is_ws[b] : 0.f;

    // complete dec_feat: df = tanh(sum_s df_part + bs)
    float dfv[16], vv[16], wcv[16];
    #pragma unroll
    for (int k = 0; k < 2; ++k) {
        const int h = hc * 8 + 128 * k;
        float d0[8], d1[8], d2[8], d3[8], bsv[8];
        load8(df_part + (size_t)(0 * BB + b) * HH + h, d0);
        load8(df_part + (size_t)(1 * BB + b) * HH + h, d1);
        load8(df_part + (size_t)(2 * BB + b) * HH + h, d2);
        load8(df_part + (size_t)(3 * BB + b) * HH + h, d3);
        load8(bs + h, bsv);
        #pragma unroll
        for (int j = 0; j < 8; ++j)
            dfv[8 * k + j] = ftanh(d0[j] + d1[j] + d2[j] + d3[j] + bsv[j]);
        load8(v + h, vv + 8 * k);
        load8(wc + h, wcv + 8 * k);
    }

    const uint4* ep0 = encb + (size_t)(b * LL + l0 + lsub) * 32 + hc;

    float s = 0.f;
    float cacc[16];
    #pragma unroll
    for (int j = 0; j < 16; ++j) cacc[j] = 0.f;

    // depth-1 software pipeline over 16 macro-iterations (4 rows each)
    auto scal = [&](int mi, float& cv, float& msk) {
        const int l = l0 + mi * 4 + lsub;
        const int idx = b * LL + l;
        msk = mask[idx];
        if (prev_t >= 0) {
            const float a = fexp(e_prev[idx]) * msk * iSprev;
            cv = cov[idx] + a;
            if (hc == 0) {
                cov[idx] = cv;
                attns[((size_t)prev_t * BB + b) * LL + l] = a;
            }
        } else {
            cv = 0.f;
            if (hc == 0) cov[idx] = 0.f;
        }
    };

    float cvA, mskA;
    scal(0, cvA, mskA);
    uint4 eA0 = ep0[0], eA1 = ep0[16];

    for (int mi = 0; mi < LCHUNK / 16; ++mi) {   // 16 iterations
        float cvB = 0.f, mskB = 0.f;
        uint4 eB0 = {0,0,0,0}, eB1 = {0,0,0,0};
        if (mi < LCHUNK / 16 - 1) {
            scal(mi + 1, cvB, mskB);
            const uint4* epn = ep0 + (mi + 1) * 128;
            eB0 = epn[0]; eB1 = epn[16];
        }

        float fe[16];
        bf8x(eA0, fe); bf8x(eA1, fe + 8);
        float pp = 0.f;
        #pragma unroll
        for (int j = 0; j < 16; ++j)
            pp += vv[j] * ftanh(fe[j] + dfv[j] + cvA * wcv[j]);
        pp += __shfl_xor(pp, 1);
        pp += __shfl_xor(pp, 2);
        pp += __shfl_xor(pp, 4);
        pp += __shfl_xor(pp, 8);
        const int l = l0 + mi * 4 + lsub;
        if (hc == 0) e_cur[b * LL + l] = pp;

        const float w = fexp(pp) * mskA;   // bounded e -> no max shift
        s += w;
        #pragma unroll
        for (int j = 0; j < 16; ++j) cacc[j] += w * fe[j];
        cvA = cvB; mskA = mskB; eA0 = eB0; eA1 = eB1;
    }

    #pragma unroll
    for (int off = 16; off <= 32; off <<= 1) {
        s += __shfl_xor(s, off);
        #pragma unroll
        for (int j = 0; j < 16; ++j) cacc[j] += __shfl_xor(cacc[j], off);
    }

    __shared__ float lsum[4];
    __shared__ float lctx[4][HH];
    if (lsub == 0) {
        #pragma unroll
        for (int k = 0; k < 2; ++k)
            #pragma unroll
            for (int j = 0; j < 8; ++j)
                lctx[wave][hc * 8 + 128 * k + j] = cacc[k * 8 + j];
    }
    if (lane == 0) lsum[wave] = s;
    __syncthreads();

    const int pidx = chunk * BB + b;
    ctxp[(size_t)pidx * HH + tid] =
        lctx[0][tid] + lctx[1][tid] + lctx[2][tid] + lctx[3][tid];
    if (tid == 0)
        sp[pidx] = lsum[0] + lsum[1] + lsum[2] + lsum[3];
}

// ---------------------------------------------------------------------------
// K3: batched outs + pgens + (for t==T-1 blocks) the final epilogue.
// Grid 512 blocks = (t, 8-batch slice), 512 threads, LDS 37 KB.
// ---------------------------------------------------------------------------
__global__ __launch_bounds__(512) void out_kernel(
    const float* __restrict__ h_hist, const float* __restrict__ ctx_hist,
    const float* __restrict__ c_hist, const float* __restrict__ x_hist,
    const float* __restrict__ Wo, const float* __restrict__ bo,
    const float* __restrict__ Wp, const float* __restrict__ bp,
    const float* __restrict__ e_ws, const float* __restrict__ mask,
    const float* __restrict__ is_ws,
    float* __restrict__ outs, float* __restrict__ pgens,
    float* __restrict__ attns, float* __restrict__ cov,
    float* __restrict__ c_out, float* __restrict__ h_out)
{
    const int t = blockIdx.x >> 3;
    const int b8 = blockIdx.x & 7;
    const int tid = threadIdx.x;
    __shared__ float hs[8 * 256], cts[8 * 256], cs2[8 * 256], xs[8 * 128];
    __shared__ float zbuf[8 * 256];

    for (int i = tid; i < 8 * 256; i += 512) {
        const int bl = i >> 8, j = i & 255;
        const size_t row = ((size_t)t * BB + b8 * 8 + bl) * HH;
        hs[i] = h_hist[row + j];
        cts[i] = ctx_hist[row + j];
        cs2[i] = c_hist[row + j];
    }
    for (int i = tid; i < 8 * 128; i += 512) {
        const int bl = i >> 7, j = i & 127;
        xs[i] = x_hist[((size_t)t * BB + b8 * 8 + bl) * EE + j];
    }
    __syncthreads();

    {
        const int j = tid & 255, rh = tid >> 8;
        float acc[8];
        #pragma unroll
        for (int bl = 0; bl < 8; ++bl) acc[bl] = 0.f;
        const int r0 = rh * 128;
        #pragma unroll 4
        for (int r = r0; r < r0 + 128; ++r) {
            const float w0 = Wo[(size_t)r * HH + j];
            const float w1 = Wo[(size_t)(256 + r) * HH + j];
            #pragma unroll
            for (int bl = 0; bl < 8; ++bl)
                acc[bl] += hs[bl * 256 + r] * w0 + cts[bl * 256 + r] * w1;
        }
        if (rh) {
            #pragma unroll
            for (int bl = 0; bl < 8; ++bl) zbuf[bl * 256 + j] = acc[bl];
        }
        __syncthreads();
        if (!rh) {
            #pragma unroll
            for (int bl = 0; bl < 8; ++bl)
                outs[((size_t)t * BB + b8 * 8 + bl) * HH + j] =
                    acc[bl] + zbuf[bl * 256 + j] + bo[j];
        }
    }

    {
        const int bl = tid >> 6, r64 = tid & 63;
        float pp = 0.f;
        for (int i = r64; i < 256; i += 64)
            pp += cts[bl * 256 + i] * Wp[i] + cs2[bl * 256 + i] * Wp[256 + i]
                + hs[bl * 256 + i] * Wp[512 + i];
        for (int i = r64; i < 128; i += 64)
            pp += xs[bl * 128 + i] * Wp[768 + i];
        #pragma unroll
        for (int off = 32; off; off >>= 1) pp += __shfl_xor(pp, off);
        if (r64 == 0)
            pgens[(size_t)t * BB + b8 * 8 + bl] = fsig(pp + bp[0]);
    }

    // ---- final-step epilogue (8 blocks): attns[T-1], cov, c/h outputs ----
    if (t == T_STEPS - 1) {
        const float* e_last = e_ws + (size_t)((T_STEPS - 1) & 1) * BB * LL;
        for (int bl = 0; bl < 8; ++bl) {
            const int b = b8 * 8 + bl;
            const float iS = is_ws[b];
            for (int i = tid; i < LL; i += 512) {
                const int idx = b * LL + i;
                const float a = fexp(e_last[idx]) * mask[idx] * iS;
                attns[((size_t)(T_STEPS - 1) * BB + b) * LL + i] = a;
                cov[idx] += a;
            }
        }
        for (int i = tid; i < 8 * HH; i += 512) {
            const int bl = i >> 8, j = i & 255;
            const int b = b8 * 8 + bl;
            c_out[(size_t)b * HH + j] = cs2[bl * 256 + j];
            h_out[(size_t)b * HH + j] = hs[bl * 256 + j];
        }
    }
}

extern "C" void kernel_launch(void* const* d_in, const int* in_sizes, int n_in,
                              void* d_out, int out_size, void* d_ws, size_t ws_size,
                              hipStream_t stream) {
    const float* dec_in = (const float*)d_in[0];
    const float* init_c = (const float*)d_in[1];
    const float* init_h = (const float*)d_in[2];
    const float* enc    = (const float*)d_in[3];
    const float* mask   = (const float*)d_in[4];
    const float* Wx = (const float*)d_in[5];
    const float* bx = (const float*)d_in[6];
    const float* Wl = (const float*)d_in[7];
    const float* bl = (const float*)d_in[8];
    const float* Ws = (const float*)d_in[9];
    const float* bs = (const float*)d_in[10];
    const float* v  = (const float*)d_in[11];
    const float* wc = (const float*)d_in[12];
    const float* Wp = (const float*)d_in[13];
    const float* bp = (const float*)d_in[14];
    const float* Wo = (const float*)d_in[15];
    const float* bo = (const float*)d_in[16];

    float* out   = (float*)d_out;
    float* outs  = out;                                   // T*B*H
    float* c_out = outs + (size_t)T_STEPS * BB * HH;      // B*H
    float* h_out = c_out + BB * HH;                       // B*H
    float* attns = h_out + BB * HH;                       // T*B*L
    float* pgens = attns + (size_t)T_STEPS * BB * LL;     // T*B
    float* cov   = pgens + T_STEPS * BB;                  // B*L

    float* ws     = (float*)d_ws;
    uint4* encb   = (uint4*)ws;                           // B*L*H bf16
    float* w      = ws + (size_t)BB * LL * HH / 2;
    float* e_ws   = w;   w += 2 * BB * LL;
    float* sp     = w;   w += NCHUNK * BB;
    float* ctxp   = w;   w += (size_t)NCHUNK * BB * HH;
    float* x_hist = w;   w += (size_t)T_STEPS * BB * EE;
    float* df_part = w;  w += 4 * BB * HH;
    float* is_ws  = w;   w += BB;
    float* ctx_hist = w; w += (size_t)T_STEPS * BB * HH;
    float* c_hist = w;   w += (size_t)T_STEPS * BB * HH;
    float* h_hist = w;   w += (size_t)T_STEPS * BB * HH;

    conv_kernel<<<4096, 256, 0, stream>>>((const float4*)enc, encb);

    for (int t = 0; t < T_STEPS; ++t) {
        step_kernel<<<256, 512, 0, stream>>>(dec_in, init_c, init_h, sp, ctxp,
            Wx, bx, Wl, bl, Ws,
            ctx_hist, x_hist, c_hist, h_hist, df_part, is_ws, t);
        attn_kernel<<<NCHUNK * BB, 256, 0, stream>>>(encb, mask, cov, df_part,
            bs, v, wc, e_ws, attns, is_ws, sp, ctxp, t);
    }
    step_kernel<<<256, 512, 0, stream>>>(dec_in, init_c, init_h, sp, ctxp,
        Wx, bx, Wl, bl, Ws,
        ctx_hist, x_hist, c_hist, h_hist, df_part, is_ws, T_STEPS);
    out_kernel<<<512, 512, 0, stream>>>(h_hist, ctx_hist, c_hist, x_hist,
        Wo, bo, Wp, bp, e_ws, mask, is_ws,
        outs, pgens, attns, cov, c_out, h_out);
}